// Round 1
// 1061.745 us; speedup vs baseline: 1.1112x; 1.1112x over previous
//
#include <hip/hip_runtime.h>
#include <cstdint>
#include <cstddef>

#define D_MODEL 512
#define NHEADS  8
#define EDIM    64
#define BATCH   8
#define LSEQ    4096

typedef unsigned short u16;
typedef __attribute__((ext_vector_type(8))) short short8;
typedef __attribute__((ext_vector_type(4))) float f32x4;

// ===================== fp32 -> 2-term bf16 split ===========================
__device__ __forceinline__ u16 bf16_rne(float x) {
  unsigned int u = __float_as_uint(x);
  u += 0x7FFFu + ((u >> 16) & 1u);
  return (u16)(u >> 16);
}
__device__ __forceinline__ void split2(float x, u16& h, u16& l) {
  h = bf16_rne(x);
  float hf = __uint_as_float((unsigned int)h << 16);
  l = bf16_rne(x - hf);
}

// X (fp32, Mchunk x 512) -> 2 bf16 planes (h, l)
__global__ __launch_bounds__(256) void cvt_x(
    const float* __restrict__ X, u16* __restrict__ P, int planeStride) {
  size_t i = ((size_t)blockIdx.x * 256 + threadIdx.x) * 4;
  float4 x = *(const float4*)(X + i);
  ushort4 h, l;
  split2(x.x, h.x, l.x);
  split2(x.y, h.y, l.y);
  split2(x.z, h.z, l.z);
  split2(x.w, h.w, l.w);
  *(ushort4*)(P + i) = h;
  *(ushort4*)(P + planeStride + i) = l;
}

// W (512x512 fp32, k-major) -> transposed planes WT[n][k] (h,l), 3 weights
__global__ __launch_bounds__(256) void cvt_w(
    const float* __restrict__ W0, const float* __restrict__ W1,
    const float* __restrict__ W2, u16* __restrict__ out) {
  const float* W = (blockIdx.z == 0) ? W0 : ((blockIdx.z == 1) ? W1 : W2);
  u16* P = out + (size_t)blockIdx.z * 524288;       // 2 planes of 262144
  __shared__ float tile[64][65];
  const int k0 = blockIdx.x * 64, n0 = blockIdx.y * 64;
  const int t = threadIdx.x;
  const int tr = t >> 4, tc = (t & 15) * 4;
#pragma unroll
  for (int j = 0; j < 4; ++j) {
    int kr = tr + j * 16;
    float4 v = *(const float4*)(W + (size_t)(k0 + kr) * 512 + n0 + tc);
    tile[kr][tc + 0] = v.x; tile[kr][tc + 1] = v.y;
    tile[kr][tc + 2] = v.z; tile[kr][tc + 3] = v.w;
  }
  __syncthreads();
#pragma unroll
  for (int j = 0; j < 4; ++j) {
    int nr = tr + j * 16;
    ushort4 h, l;
    split2(tile[tc + 0][nr], h.x, l.x);
    split2(tile[tc + 1][nr], h.y, l.y);
    split2(tile[tc + 2][nr], h.z, l.z);
    split2(tile[tc + 3][nr], h.w, l.w);
    size_t off = (size_t)(n0 + nr) * 512 + k0 + tc;
    *(ushort4*)(P + off) = h;
    *(ushort4*)(P + 262144 + off) = l;
  }
}

__device__ __forceinline__ void gld_lds16(const char* g, char* l) {
  __builtin_amdgcn_global_load_lds((const __attribute__((address_space(1))) void*)g,
                                   (__attribute__((address_space(3))) void*)l, 16, 0, 0);
}

// ========== split-bf16 MFMA GEMM: Y = X @ W ================================
// 128x128 tile, BK=32, 4 waves. Fused 3-term split per k-step:
// acc += Ah*Bh + Ah*Bl + Al*Bh  (drops XlWl ~ 2^-18 rel).
// 16 k-steps, 48 MFMA per wave between one barrier pair (3x density vs the
// old 3-sweep version), and each plane tile staged exactly once (-33% bytes).
__global__ __launch_bounds__(256, 2) void gemm_mfma(
    const u16* __restrict__ XP, int xPlaneStride,
    const u16* __restrict__ WP, float* __restrict__ Y) {
  __shared__ u16 Ah[128 * 32];
  __shared__ u16 Al[128 * 32];
  __shared__ u16 Bh[128 * 32];
  __shared__ u16 Bl[128 * 32];
  const int tid = threadIdx.x;
  const int lane = tid & 63, wv = tid >> 6;
  const int wm = (wv & 1) * 64, wn = (wv >> 1) * 64;
  const int bm = blockIdx.x * 128, bn = blockIdx.y * 128;
  const int fr = lane & 15, quad = lane >> 4;
  const int sRow = tid >> 2, sColB = (tid & 3) * 16;

  f32x4 acc[16];
#pragma unroll
  for (int i = 0; i < 16; ++i) acc[i] = (f32x4){0.f, 0.f, 0.f, 0.f};

  const u16* Xh = XP;
  const u16* Xl = XP + xPlaneStride;
  const u16* Wh = WP;
  const u16* Wl = WP + 262144;

  for (int kk = 0; kk < 16; ++kk) {
#pragma unroll
    for (int j = 0; j < 2; ++j) {
      const size_t rA = (size_t)(bm + j * 64 + sRow) * 512 + kk * 32;
      const size_t rB = (size_t)(bn + j * 64 + sRow) * 512 + kk * 32;
      const int lo = (j * 256 + wv * 64) * 16;
      gld_lds16((const char*)(Xh + rA) + sColB, (char*)Ah + lo);
      gld_lds16((const char*)(Xl + rA) + sColB, (char*)Al + lo);
      gld_lds16((const char*)(Wh + rB) + sColB, (char*)Bh + lo);
      gld_lds16((const char*)(Wl + rB) + sColB, (char*)Bl + lo);
    }
    __syncthreads();
    short8 ah[4], al[4], bh[4], bl[4];
#pragma unroll
    for (int mi = 0; mi < 4; ++mi) {
      ah[mi] = *(const short8*)&Ah[(wm + mi * 16 + fr) * 32 + quad * 8];
      al[mi] = *(const short8*)&Al[(wm + mi * 16 + fr) * 32 + quad * 8];
    }
#pragma unroll
    for (int ni = 0; ni < 4; ++ni) {
      bh[ni] = *(const short8*)&Bh[(wn + ni * 16 + fr) * 32 + quad * 8];
      bl[ni] = *(const short8*)&Bl[(wn + ni * 16 + fr) * 32 + quad * 8];
    }
#pragma unroll
    for (int mi = 0; mi < 4; ++mi)
#pragma unroll
      for (int ni = 0; ni < 4; ++ni)
        acc[mi * 4 + ni] = __builtin_amdgcn_mfma_f32_16x16x32_bf16(
            ah[mi], bh[ni], acc[mi * 4 + ni], 0, 0, 0);
#pragma unroll
    for (int mi = 0; mi < 4; ++mi)
#pragma unroll
      for (int ni = 0; ni < 4; ++ni)
        acc[mi * 4 + ni] = __builtin_amdgcn_mfma_f32_16x16x32_bf16(
            ah[mi], bl[ni], acc[mi * 4 + ni], 0, 0, 0);
#pragma unroll
    for (int mi = 0; mi < 4; ++mi)
#pragma unroll
      for (int ni = 0; ni < 4; ++ni)
        acc[mi * 4 + ni] = __builtin_amdgcn_mfma_f32_16x16x32_bf16(
            al[mi], bh[ni], acc[mi * 4 + ni], 0, 0, 0);
    __syncthreads();
  }
#pragma unroll
  for (int mi = 0; mi < 4; ++mi)
#pragma unroll
    for (int ni = 0; ni < 4; ++ni) {
      const f32x4 a = acc[mi * 4 + ni];
      float* yp = Y + (size_t)(bm + wm + mi * 16 + quad * 4) * 512 + (bn + wn + ni * 16 + fr);
#pragma unroll
      for (int r = 0; r < 4; ++r) yp[(size_t)r * 512] = a[r];
    }
}

// ================= QK_sample -> M, half-row per pass =======================
// hg selects heads hg*4..hg*4+3 => K columns [hg*256, hg*256+256).
// Per-batch working set = 4096 rows x 1KB = 4MB = one XCD's L2.
// lane = head(4) x sub(16), each lane owns 4 elems; 4-shuffle reduction.
__global__ __launch_bounds__(256) void qk_sample_half(
    const float* __restrict__ Q, const float* __restrict__ K,
    const int* __restrict__ sidx, float* __restrict__ M, int S, int hg) {
  const int blk = blockIdx.x;
  const int lane = threadIdx.x & 63;
  const int b = blk & 7;                      // XCD swizzle: batch <-> XCD
  const int q = ((blk >> 3) << 2) + (threadIdx.x >> 6);
  const int sub = lane & 15, hl = lane >> 4;
  const int h = hg * 4 + hl;
  const int col = hg * 256 + hl * 64 + sub * 4;

  float4 qv = *(const float4*)(Q + ((size_t)b * LSEQ + q) * D_MODEL + col);
  const float* Kb = K + (size_t)b * LSEQ * D_MODEL + col;
  const int* sp = sidx + (size_t)q * S;

  float mx = -3.4e38f, sum = 0.0f;
  float4 ka = *(const float4*)(Kb + (size_t)sp[0] * D_MODEL);
  for (int j = 0; j < S; ++j) {
    float4 ca = ka;
    if (j + 1 < S)
      ka = *(const float4*)(Kb + (size_t)sp[j + 1] * D_MODEL);
    float p = qv.x * ca.x + qv.y * ca.y + qv.z * ca.z + qv.w * ca.w;
    p += __shfl_xor(p, 1, 64);
    p += __shfl_xor(p, 2, 64);
    p += __shfl_xor(p, 4, 64);
    p += __shfl_xor(p, 8, 64);   // 16-lane group done
    mx = fmaxf(mx, p);
    sum += p;
  }
  if (sub == 0) M[((size_t)(b * NHEADS + h)) * LSEQ + q] = mx - sum / (float)S;
}

// ===================== top-U indices per (b,h) =============================
__global__ __launch_bounds__(256) void topk_kernel(
    const float* __restrict__ M, int* __restrict__ Mtop, int U) {
  __shared__ float vals[LSEQ];
  __shared__ float rmax[256];
  __shared__ int ridx[256];
  int bh = blockIdx.x;
  int t = threadIdx.x;
  for (int i = t; i < LSEQ; i += 256) vals[i] = M[(size_t)bh * LSEQ + i];
  __syncthreads();
  for (int it = 0; it < U; ++it) {
    float best = -3.4e38f; int bi = -1;
    for (int i = t; i < LSEQ; i += 256) {
      float v = vals[i];
      if (v > best) { best = v; bi = i; }
    }
    rmax[t] = best; ridx[t] = bi;
    __syncthreads();
    for (int s = 128; s > 0; s >>= 1) {
      if (t < s) {
        if (rmax[t + s] > rmax[t]) { rmax[t] = rmax[t + s]; ridx[t] = ridx[t + s]; }
      }
      __syncthreads();
    }
    if (t == 0) {
      Mtop[(size_t)bh * U + it] = ridx[0];
      vals[ridx[0]] = -3.4e38f;
    }
    __syncthreads();
  }
}

// ============== flash attention over top-U rows, key-split =================
// __launch_bounds__(256,2): q4[16]+c4[16] = 128 live VGPRs; the default
// heuristic capped the budget at 84 and spilled (rocprof VGPR_Count=84).
__global__ __launch_bounds__(256, 2) void attn_flash(
    const float* __restrict__ Q, const float* __restrict__ K,
    const float* __restrict__ V, const int* __restrict__ Mtop,
    float* __restrict__ part_ctx, float* __restrict__ part_m,
    float* __restrict__ part_l, int U, int nsplit, int chunks_per_block) {
  __shared__ float Ks[64 * 64];
  __shared__ float Vs[64 * 64];
  __shared__ float Mw[4][64], Lw[4][64];
  const int bh = blockIdx.y, split = blockIdx.x;
  const int h = bh & (NHEADS - 1), b = bh >> 3;
  const int t = threadIdx.x, w = t >> 6, lane = t & 63;

  int qrow = (lane < U) ? Mtop[(size_t)bh * U + lane] : 0;
  const float4* Qp = (const float4*)(Q + ((size_t)(b * LSEQ) + qrow) * D_MODEL + h * EDIM);
  float4 q4[16], c4[16];
#pragma unroll
  for (int i = 0; i < 16; ++i) q4[i] = Qp[i];
#pragma unroll
  for (int i = 0; i < 16; ++i) c4[i] = make_float4(0.f, 0.f, 0.f, 0.f);
  float m = -1e30f, l = 0.0f;

  const int k_base = split * (chunks_per_block * 64);
  for (int c = 0; c < chunks_per_block; ++c) {
    const int k0 = k_base + c * 64;
    const float4* Kg = (const float4*)(K + ((size_t)(b * LSEQ) + k0) * D_MODEL + h * EDIM);
    const float4* Vg = (const float4*)(V + ((size_t)(b * LSEQ) + k0) * D_MODEL + h * EDIM);
#pragma unroll
    for (int i = 0; i < 4; ++i) {
      int f = t + i * 256;
      int row = f >> 4, col4 = f & 15;
      ((float4*)Ks)[f] = Kg[(size_t)row * 128 + col4];
      ((float4*)Vs)[f] = Vg[(size_t)row * 128 + col4];
    }
    __syncthreads();
#pragma unroll 1
    for (int rr = 0; rr < 16; ++rr) {
      const int r = w * 16 + rr;
      const float4* kr = (const float4*)&Ks[r * 64];
      float s = 0.0f;
#pragma unroll
      for (int i = 0; i < 16; ++i) {
        float4 kv = kr[i];
        s += q4[i].x * kv.x + q4[i].y * kv.y + q4[i].z * kv.z + q4[i].w * kv.w;
      }
      s *= 0.125f;
      if (s > m) {
        float f = __expf(m - s);
        l *= f;
#pragma unroll
        for (int i = 0; i < 16; ++i) {
          c4[i].x *= f; c4[i].y *= f; c4[i].z *= f; c4[i].w *= f;
        }
        m = s;
      }
      float p = __expf(s - m);
      l += p;
      const float4* vr = (const float4*)&Vs[r * 64];
#pragma unroll
      for (int i = 0; i < 16; ++i) {
        float4 vv = vr[i];
        c4[i].x += p * vv.x; c4[i].y += p * vv.y;
        c4[i].z += p * vv.z; c4[i].w += p * vv.w;
      }
    }
    __syncthreads();
  }

  Mw[w][lane] = m; Lw[w][lane] = l;
  __syncthreads();
  float Mg = fmaxf(fmaxf(Mw[0][lane], Mw[1][lane]), fmaxf(Mw[2][lane], Mw[3][lane]));
  float Lg = 0.0f;
#pragma unroll
  for (int w2 = 0; w2 < 4; ++w2) Lg += Lw[w2][lane] * __expf(Mw[w2][lane] - Mg);
  float sw = __expf(m - Mg);
  float* acc = Ks;
  for (int w2 = 0; w2 < 4; ++w2) {
    if (w == w2) {
#pragma unroll
      for (int i = 0; i < 16; ++i) {
        int e = i * 4;
        if (w2 == 0) {
          acc[(e + 0) * 64 + lane] = c4[i].x * sw;
          acc[(e + 1) * 64 + lane] = c4[i].y * sw;
          acc[(e + 2) * 64 + lane] = c4[i].z * sw;
          acc[(e + 3) * 64 + lane] = c4[i].w * sw;
        } else {
          acc[(e + 0) * 64 + lane] += c4[i].x * sw;
          acc[(e + 1) * 64 + lane] += c4[i].y * sw;
          acc[(e + 2) * 64 + lane] += c4[i].z * sw;
          acc[(e + 3) * 64 + lane] += c4[i].w * sw;
        }
      }
    }
    __syncthreads();
  }
  if (w == 0 && lane < U) {
    part_m[(size_t)(bh * nsplit + split) * 64 + lane] = Mg;
    part_l[(size_t)(bh * nsplit + split) * 64 + lane] = Lg;
  }
  float* pc = part_ctx + (size_t)(bh * nsplit + split) * 4096;
#pragma unroll
  for (int i = 0; i < 16; ++i) {
    int f = t + i * 256;
    pc[f] = acc[f];
  }
}

// =================== combine key-split flash partials ======================
__global__ __launch_bounds__(256) void attn_combine(
    const float* __restrict__ part_ctx, const float* __restrict__ part_m,
    const float* __restrict__ part_l, float* __restrict__ ctxTop,
    int U, int nsplit) {
  __shared__ float F[16][64];
  const int bh = blockIdx.x;
  const int t = threadIdx.x, lane = t & 63, grp = t >> 6;
  if (grp == 0) {
    float M = -3.4e38f;
    for (int s = 0; s < nsplit; ++s)
      M = fmaxf(M, part_m[(size_t)(bh * nsplit + s) * 64 + lane]);
    float L = 0.0f;
    for (int s = 0; s < nsplit; ++s)
      L += part_l[(size_t)(bh * nsplit + s) * 64 + lane] *
           __expf(part_m[(size_t)(bh * nsplit + s) * 64 + lane] - M);
    float invL = 1.0f / L;
    for (int s = 0; s < nsplit; ++s)
      F[s][lane] = __expf(part_m[(size_t)(bh * nsplit + s) * 64 + lane] - M) * invL;
  }
  __syncthreads();
  for (int ei = 0; ei < 16; ++ei) {
    int e = grp * 16 + ei;
    float acc = 0.0f;
    for (int s = 0; s < nsplit; ++s)
      acc += F[s][lane] * part_ctx[(size_t)(bh * nsplit + s) * 4096 + e * 64 + lane];
    if (lane < U) ctxTop[((size_t)bh * U + lane) * 64 + e] = acc;
  }
}

// ====================== V.mean over keys per (b,h) =========================
__global__ __launch_bounds__(256) void vmean_kernel(
    const float* __restrict__ V, float* __restrict__ Vm) {
  __shared__ float part[4][EDIM];
  int bh = blockIdx.x;
  int h = bh & (NHEADS - 1), b = bh >> 3;
  int t = threadIdx.x;
  int e = t & 63, c = t >> 6;
  float s = 0.0f;
  for (int k = c * (LSEQ / 4); k < (c + 1) * (LSEQ / 4); ++k)
    s += V[((size_t)b * LSEQ + k) * D_MODEL + h * EDIM + e];
  part[c][e] = s;
  __syncthreads();
  if (c == 0)
    Vm[(size_t)bh * EDIM + e] =
        (part[0][e] + part[1][e] + part[2][e] + part[3][e]) * (1.0f / (float)LSEQ);
}

// ============ base_out[b] = concat_h(Vmean[b,h]) @ W_out + b_out ===========
__global__ __launch_bounds__(256) void base_out_kernel(
    const float* __restrict__ Vm, const float* __restrict__ Wout,
    const float* __restrict__ bout, float* __restrict__ base) {
  __shared__ float cb[D_MODEL];
  int b = blockIdx.x;
  int t = threadIdx.x;
  for (int d = t; d < D_MODEL; d += 256) cb[d] = Vm[(size_t)b * D_MODEL + d];
  __syncthreads();
  for (int n = t; n < D_MODEL; n += 256) {
    float s = bout[n];
    for (int d = 0; d < D_MODEL; ++d) s += cb[d] * Wout[(size_t)d * D_MODEL + n];
    base[(size_t)b * D_MODEL + n] = s;
  }
}

// ================== broadcast base row into all output rows ================
__global__ __launch_bounds__(256) void fill_out(
    const float* __restrict__ base, float* __restrict__ out) {
  size_t i = (size_t)blockIdx.x * 256 + threadIdx.x;
  int n4 = (int)(i & 127);
  size_t bq = i >> 7;
  int b = (int)(bq >> 12);
  float4 v = ((const float4*)base)[(size_t)b * 128 + n4];
  ((float4*)out)[i] = v;
}

// ====== add (ctxTop - Vmean) @ W_out[h-slice] into the top rows ============
__global__ __launch_bounds__(256) void delta_out(
    const float* __restrict__ ctxTop, const float* __restrict__ Vm,
    const int* __restrict__ Mtop, const float* __restrict__ Wout,
    float* __restrict__ out, int U) {
  __shared__ float dlt[EDIM];
  int blk = blockIdx.x;
  int u = blk % U, bh = blk / U;
  int h = bh & (NHEADS - 1), b = bh >> 3;
  int q = Mtop[(size_t)bh * U + u];
  int t = threadIdx.x;
  if (t < EDIM)
    dlt[t] = ctxTop[((size_t)bh * U + u) * EDIM + t] - Vm[(size_t)bh * EDIM + t];
  __syncthreads();
  float* orow = out + ((size_t)b * LSEQ + q) * D_MODEL;
  for (int n = t; n < D_MODEL; n += 256) {
    float s = 0.0f;
#pragma unroll
    for (int e = 0; e < EDIM; ++e) s += dlt[e] * Wout[(size_t)(h * EDIM + e) * D_MODEL + n];
    atomicAdd(&orow[n], s);
  }
}

// ===========================================================================
extern "C" void kernel_launch(void* const* d_in, const int* in_sizes, int n_in,
                              void* d_out, int out_size, void* d_ws, size_t ws_size,
                              hipStream_t stream) {
  const float* query  = (const float*)d_in[0];
  const float* key_in = (const float*)d_in[1];
  const float* value  = (const float*)d_in[2];
  const float* W_Q    = (const float*)d_in[3];
  const float* W_K    = (const float*)d_in[4];
  const float* W_V    = (const float*)d_in[5];
  const float* W_out  = (const float*)d_in[6];
  const float* b_out  = (const float*)d_in[7];
  const int*   sidx   = (const int*)d_in[8];
  float* out = (float*)d_out;

  const int S = in_sizes[8] / LSEQ;   // 41
  const int U = S;

  char* ws = (char*)d_ws;
  size_t o = 0;
  float* Qf     = (float*)(ws + o); o += (size_t)BATCH * LSEQ * D_MODEL * 4;
  float* Kf     = (float*)(ws + o); o += (size_t)BATCH * LSEQ * D_MODEL * 4;
  float* Vf     = (float*)(ws + o); o += (size_t)BATCH * LSEQ * D_MODEL * 4;
  int*   Mtop   = (int*)  (ws + o); o += ((size_t)64 * U * 4 + 255) & ~255ULL;
  float* ctxTop = (float*)(ws + o); o += ((size_t)64 * U * EDIM * 4 + 255) & ~255ULL;
  float* Vm     = (float*)(ws + o); o += 16384;
  float* baseO  = (float*)(ws + o); o += 16384;
  u16*   Wpl    = (u16*)  (ws + o); o += (size_t)3 * 524288 * 2;   // 3 MB
  size_t unionOff = o;   // X planes / M / flash partials (disjoint lifetimes)

  // adaptive M-chunking so the 2 split planes fit
  int nchunk = 1;
  while (nchunk < 16 &&
         unionOff + 2 * ((size_t)(32768 / nchunk) * 512 * 2) > ws_size)
    nchunk <<= 1;
  const int Mchunk = 32768 / nchunk;
  u16* planes = (u16*)(ws + unionOff);
  const int planeStride = Mchunk * 512;

  float* M = (float*)(ws + unionOff);            // 1 MB, after gemms
  int nsplit = 16;
  for (;;) {
    size_t need = unionOff + 2 * ((size_t)64 * nsplit * 64 * 4)
                  + (size_t)64 * nsplit * 4096 * 4;
    if (need <= ws_size || nsplit == 1) break;
    nsplit >>= 1;
  }
  float* part_m   = (float*)(ws + unionOff);
  float* part_l   = part_m + (size_t)64 * nsplit * 64;
  float* part_ctx = part_l + (size_t)64 * nsplit * 64;
  const int chunks_per_block = 64 / nsplit;

  // ---- projections via split-bf16 MFMA (fused 3-term, single K-sweep) ----
  cvt_w<<<dim3(8, 8, 3), 256, 0, stream>>>(W_Q, W_K, W_V, Wpl);
  const float* Xsrc[3] = {query, key_in, value};
  float* Ydst[3] = {Qf, Kf, Vf};
  for (int g = 0; g < 3; ++g) {
    for (int c = 0; c < nchunk; ++c) {
      const float* xc = Xsrc[g] + (size_t)c * Mchunk * 512;
      float* yc = Ydst[g] + (size_t)c * Mchunk * 512;
      cvt_x<<<(Mchunk * 512) / 1024, 256, 0, stream>>>(xc, planes, planeStride);
      gemm_mfma<<<dim3(Mchunk / 128, 4), 256, 0, stream>>>(
          planes, planeStride, Wpl + (size_t)g * 524288, yc);
    }
  }

  qk_sample_half<<<(BATCH * LSEQ) / 4, 256, 0, stream>>>(Qf, Kf, sidx, M, S, 0);
  qk_sample_half<<<(BATCH * LSEQ) / 4, 256, 0, stream>>>(Qf, Kf, sidx, M, S, 1);
  topk_kernel<<<BATCH * NHEADS, 256, 0, stream>>>(M, Mtop, U);
  attn_flash<<<dim3(nsplit, BATCH * NHEADS), 256, 0, stream>>>(
      Qf, Kf, Vf, Mtop, part_ctx, part_m, part_l, U, nsplit, chunks_per_block);
  attn_combine<<<BATCH * NHEADS, 256, 0, stream>>>(
      part_ctx, part_m, part_l, ctxTop, U, nsplit);
  vmean_kernel<<<BATCH * NHEADS, 256, 0, stream>>>(Vf, Vm);
  base_out_kernel<<<BATCH, 256, 0, stream>>>(Vm, W_out, b_out, baseO);
  fill_out<<<(BATCH * LSEQ * (D_MODEL / 4)) / 256, 256, 0, stream>>>(baseO, out);
  delta_out<<<BATCH * NHEADS * U, 256, 0, stream>>>(ctxTop, Vm, Mtop, W_out, out, U);
}

// Round 2
// 998.397 us; speedup vs baseline: 1.1817x; 1.0634x over previous
//
#include <hip/hip_runtime.h>
#include <cstdint>
#include <cstddef>

#define D_MODEL 512
#define NHEADS  8
#define EDIM    64
#define BATCH   8
#define LSEQ    4096

typedef unsigned short u16;
typedef __attribute__((ext_vector_type(8))) short short8;
typedef __attribute__((ext_vector_type(4))) float f32x4;

// ===================== fp32 -> 2-term bf16 split ===========================
__device__ __forceinline__ u16 bf16_rne(float x) {
  unsigned int u = __float_as_uint(x);
  u += 0x7FFFu + ((u >> 16) & 1u);
  return (u16)(u >> 16);
}
__device__ __forceinline__ void split2(float x, u16& h, u16& l) {
  h = bf16_rne(x);
  float hf = __uint_as_float((unsigned int)h << 16);
  l = bf16_rne(x - hf);
}

// X (fp32, Mchunk x 512) -> 2 bf16 planes (h, l)
__global__ __launch_bounds__(256) void cvt_x(
    const float* __restrict__ X, u16* __restrict__ P, int planeStride) {
  size_t i = ((size_t)blockIdx.x * 256 + threadIdx.x) * 4;
  float4 x = *(const float4*)(X + i);
  ushort4 h, l;
  split2(x.x, h.x, l.x);
  split2(x.y, h.y, l.y);
  split2(x.z, h.z, l.z);
  split2(x.w, h.w, l.w);
  *(ushort4*)(P + i) = h;
  *(ushort4*)(P + planeStride + i) = l;
}

// W (512x512 fp32, k-major) -> transposed planes WT[n][k] (h,l), 3 weights
__global__ __launch_bounds__(256) void cvt_w(
    const float* __restrict__ W0, const float* __restrict__ W1,
    const float* __restrict__ W2, u16* __restrict__ out) {
  const float* W = (blockIdx.z == 0) ? W0 : ((blockIdx.z == 1) ? W1 : W2);
  u16* P = out + (size_t)blockIdx.z * 524288;       // 2 planes of 262144
  __shared__ float tile[64][65];
  const int k0 = blockIdx.x * 64, n0 = blockIdx.y * 64;
  const int t = threadIdx.x;
  const int tr = t >> 4, tc = (t & 15) * 4;
#pragma unroll
  for (int j = 0; j < 4; ++j) {
    int kr = tr + j * 16;
    float4 v = *(const float4*)(W + (size_t)(k0 + kr) * 512 + n0 + tc);
    tile[kr][tc + 0] = v.x; tile[kr][tc + 1] = v.y;
    tile[kr][tc + 2] = v.z; tile[kr][tc + 3] = v.w;
  }
  __syncthreads();
#pragma unroll
  for (int j = 0; j < 4; ++j) {
    int nr = tr + j * 16;
    ushort4 h, l;
    split2(tile[tc + 0][nr], h.x, l.x);
    split2(tile[tc + 1][nr], h.y, l.y);
    split2(tile[tc + 2][nr], h.z, l.z);
    split2(tile[tc + 3][nr], h.w, l.w);
    size_t off = (size_t)(n0 + nr) * 512 + k0 + tc;
    *(ushort4*)(P + off) = h;
    *(ushort4*)(P + 262144 + off) = l;
  }
}

__device__ __forceinline__ void gld_lds16(const char* g, char* l) {
  __builtin_amdgcn_global_load_lds((const __attribute__((address_space(1))) void*)g,
                                   (__attribute__((address_space(3))) void*)l, 16, 0, 0);
}

// ========== split-bf16 MFMA GEMM: Y = X @ W ================================
// 128x128 tile, BK=32, 4 waves. Fused 3-term split per k-step:
// acc += Ah*Bh + Ah*Bl + Al*Bh  (drops XlWl ~ 2^-18 rel).
__global__ __launch_bounds__(256, 2) void gemm_mfma(
    const u16* __restrict__ XP, int xPlaneStride,
    const u16* __restrict__ WP, float* __restrict__ Y) {
  __shared__ u16 Ah[128 * 32];
  __shared__ u16 Al[128 * 32];
  __shared__ u16 Bh[128 * 32];
  __shared__ u16 Bl[128 * 32];
  const int tid = threadIdx.x;
  const int lane = tid & 63, wv = tid >> 6;
  const int wm = (wv & 1) * 64, wn = (wv >> 1) * 64;
  const int bm = blockIdx.x * 128, bn = blockIdx.y * 128;
  const int fr = lane & 15, quad = lane >> 4;
  const int sRow = tid >> 2, sColB = (tid & 3) * 16;

  f32x4 acc[16];
#pragma unroll
  for (int i = 0; i < 16; ++i) acc[i] = (f32x4){0.f, 0.f, 0.f, 0.f};

  const u16* Xh = XP;
  const u16* Xl = XP + xPlaneStride;
  const u16* Wh = WP;
  const u16* Wl = WP + 262144;

  for (int kk = 0; kk < 16; ++kk) {
#pragma unroll
    for (int j = 0; j < 2; ++j) {
      const size_t rA = (size_t)(bm + j * 64 + sRow) * 512 + kk * 32;
      const size_t rB = (size_t)(bn + j * 64 + sRow) * 512 + kk * 32;
      const int lo = (j * 256 + wv * 64) * 16;
      gld_lds16((const char*)(Xh + rA) + sColB, (char*)Ah + lo);
      gld_lds16((const char*)(Xl + rA) + sColB, (char*)Al + lo);
      gld_lds16((const char*)(Wh + rB) + sColB, (char*)Bh + lo);
      gld_lds16((const char*)(Wl + rB) + sColB, (char*)Bl + lo);
    }
    __syncthreads();
    short8 ah[4], al[4], bh[4], bl[4];
#pragma unroll
    for (int mi = 0; mi < 4; ++mi) {
      ah[mi] = *(const short8*)&Ah[(wm + mi * 16 + fr) * 32 + quad * 8];
      al[mi] = *(const short8*)&Al[(wm + mi * 16 + fr) * 32 + quad * 8];
    }
#pragma unroll
    for (int ni = 0; ni < 4; ++ni) {
      bh[ni] = *(const short8*)&Bh[(wn + ni * 16 + fr) * 32 + quad * 8];
      bl[ni] = *(const short8*)&Bl[(wn + ni * 16 + fr) * 32 + quad * 8];
    }
#pragma unroll
    for (int mi = 0; mi < 4; ++mi)
#pragma unroll
      for (int ni = 0; ni < 4; ++ni)
        acc[mi * 4 + ni] = __builtin_amdgcn_mfma_f32_16x16x32_bf16(
            ah[mi], bh[ni], acc[mi * 4 + ni], 0, 0, 0);
#pragma unroll
    for (int mi = 0; mi < 4; ++mi)
#pragma unroll
      for (int ni = 0; ni < 4; ++ni)
        acc[mi * 4 + ni] = __builtin_amdgcn_mfma_f32_16x16x32_bf16(
            ah[mi], bl[ni], acc[mi * 4 + ni], 0, 0, 0);
#pragma unroll
    for (int mi = 0; mi < 4; ++mi)
#pragma unroll
      for (int ni = 0; ni < 4; ++ni)
        acc[mi * 4 + ni] = __builtin_amdgcn_mfma_f32_16x16x32_bf16(
            al[mi], bh[ni], acc[mi * 4 + ni], 0, 0, 0);
    __syncthreads();
  }
#pragma unroll
  for (int mi = 0; mi < 4; ++mi)
#pragma unroll
    for (int ni = 0; ni < 4; ++ni) {
      const f32x4 a = acc[mi * 4 + ni];
      float* yp = Y + (size_t)(bm + wm + mi * 16 + quad * 4) * 512 + (bn + wn + ni * 16 + fr);
#pragma unroll
      for (int r = 0; r < 4; ++r) yp[(size_t)r * 512] = a[r];
    }
}

// ================= QK_sample -> M, half-row per pass =======================
__global__ __launch_bounds__(256) void qk_sample_half(
    const float* __restrict__ Q, const float* __restrict__ K,
    const int* __restrict__ sidx, float* __restrict__ M, int S, int hg) {
  const int blk = blockIdx.x;
  const int lane = threadIdx.x & 63;
  const int b = blk & 7;                      // XCD swizzle: batch <-> XCD
  const int q = ((blk >> 3) << 2) + (threadIdx.x >> 6);
  const int sub = lane & 15, hl = lane >> 4;
  const int h = hg * 4 + hl;
  const int col = hg * 256 + hl * 64 + sub * 4;

  float4 qv = *(const float4*)(Q + ((size_t)b * LSEQ + q) * D_MODEL + col);
  const float* Kb = K + (size_t)b * LSEQ * D_MODEL + col;
  const int* sp = sidx + (size_t)q * S;

  float mx = -3.4e38f, sum = 0.0f;
  float4 ka = *(const float4*)(Kb + (size_t)sp[0] * D_MODEL);
  for (int j = 0; j < S; ++j) {
    float4 ca = ka;
    if (j + 1 < S)
      ka = *(const float4*)(Kb + (size_t)sp[j + 1] * D_MODEL);
    float p = qv.x * ca.x + qv.y * ca.y + qv.z * ca.z + qv.w * ca.w;
    p += __shfl_xor(p, 1, 64);
    p += __shfl_xor(p, 2, 64);
    p += __shfl_xor(p, 4, 64);
    p += __shfl_xor(p, 8, 64);   // 16-lane group done
    mx = fmaxf(mx, p);
    sum += p;
  }
  if (sub == 0) M[((size_t)(b * NHEADS + h)) * LSEQ + q] = mx - sum / (float)S;
}

// ===================== top-U indices per (b,h) =============================
__global__ __launch_bounds__(256) void topk_kernel(
    const float* __restrict__ M, int* __restrict__ Mtop, int U) {
  __shared__ float vals[LSEQ];
  __shared__ float rmax[256];
  __shared__ int ridx[256];
  int bh = blockIdx.x;
  int t = threadIdx.x;
  for (int i = t; i < LSEQ; i += 256) vals[i] = M[(size_t)bh * LSEQ + i];
  __syncthreads();
  for (int it = 0; it < U; ++it) {
    float best = -3.4e38f; int bi = -1;
    for (int i = t; i < LSEQ; i += 256) {
      float v = vals[i];
      if (v > best) { best = v; bi = i; }
    }
    rmax[t] = best; ridx[t] = bi;
    __syncthreads();
    for (int s = 128; s > 0; s >>= 1) {
      if (t < s) {
        if (rmax[t + s] > rmax[t]) { rmax[t] = rmax[t + s]; ridx[t] = ridx[t + s]; }
      }
      __syncthreads();
    }
    if (t == 0) {
      Mtop[(size_t)bh * U + it] = ridx[0];
      vals[ridx[0]] = -3.4e38f;
    }
    __syncthreads();
  }
}

// ============== flash attention over top-U rows, key-split =================
// MFMA QK^T (swapped: S^T = mfma(K, Q)) + fp32 VALU PV.
// 4 waves split the 64 q-rows (16 each, one per lane&15); each wave sees all
// keys of the block, so softmax is per-64-key-tile (no per-key rescale) and
// no cross-wave combine is needed. K staged as split-bf16 [64][72] (padded,
// conflict-free ds_read_b128); Q fragments straight from global (B-operand
// of the swapped MFMA is Q rows, dim-contiguous). P stays in fp32 regs in
// exactly the lane layout VALU PV consumes (lane=q, rows=keys).
__global__ __launch_bounds__(256, 2) void attn_flash(
    const float* __restrict__ Q, const float* __restrict__ K,
    const float* __restrict__ V, const int* __restrict__ Mtop,
    float* __restrict__ part_ctx, float* __restrict__ part_m,
    float* __restrict__ part_l, int U, int nsplit, int chunks_per_block) {
  __shared__ u16 KhS[64 * 72];
  __shared__ u16 KlS[64 * 72];
  __shared__ float VsS[64 * 68];
  const int bh = blockIdx.y, split = blockIdx.x;
  const int h = bh & (NHEADS - 1), b = bh >> 3;
  const int t = threadIdx.x, w = t >> 6, lane = t & 63;
  const int fr = lane & 15, quad = lane >> 4;

  // ---- Q fragments (per lane: q-row = Mtop[w*16+fr], dims quad*8..+8, +32)
  const int qi = w * 16 + fr;
  const int qrow = (qi < U) ? Mtop[(size_t)bh * U + qi] : Mtop[(size_t)bh * U];
  const float4* Qr = (const float4*)(Q + ((size_t)(b * LSEQ) + qrow) * D_MODEL + h * EDIM);
  float4 qa = Qr[quad * 2], qb = Qr[quad * 2 + 1];
  float4 qc = Qr[quad * 2 + 8], qd = Qr[quad * 2 + 9];
  short8 qh0, ql0, qh1, ql1;
  {
    u16 hh, ll;
    split2(qa.x, hh, ll); qh0[0] = (short)hh; ql0[0] = (short)ll;
    split2(qa.y, hh, ll); qh0[1] = (short)hh; ql0[1] = (short)ll;
    split2(qa.z, hh, ll); qh0[2] = (short)hh; ql0[2] = (short)ll;
    split2(qa.w, hh, ll); qh0[3] = (short)hh; ql0[3] = (short)ll;
    split2(qb.x, hh, ll); qh0[4] = (short)hh; ql0[4] = (short)ll;
    split2(qb.y, hh, ll); qh0[5] = (short)hh; ql0[5] = (short)ll;
    split2(qb.z, hh, ll); qh0[6] = (short)hh; ql0[6] = (short)ll;
    split2(qb.w, hh, ll); qh0[7] = (short)hh; ql0[7] = (short)ll;
    split2(qc.x, hh, ll); qh1[0] = (short)hh; ql1[0] = (short)ll;
    split2(qc.y, hh, ll); qh1[1] = (short)hh; ql1[1] = (short)ll;
    split2(qc.z, hh, ll); qh1[2] = (short)hh; ql1[2] = (short)ll;
    split2(qc.w, hh, ll); qh1[3] = (short)hh; ql1[3] = (short)ll;
    split2(qd.x, hh, ll); qh1[4] = (short)hh; ql1[4] = (short)ll;
    split2(qd.y, hh, ll); qh1[5] = (short)hh; ql1[5] = (short)ll;
    split2(qd.z, hh, ll); qh1[6] = (short)hh; ql1[6] = (short)ll;
    split2(qd.w, hh, ll); qh1[7] = (short)hh; ql1[7] = (short)ll;
  }

  float4 c4[16];
#pragma unroll
  for (int i = 0; i < 16; ++i) c4[i] = make_float4(0.f, 0.f, 0.f, 0.f);
  float m = -1e30f, l = 0.0f;

  // staging coords: thread covers key-row r, float4s (cg + 4*i)
  const int r = t >> 2, cg = t & 3;

  const int k_base = split * (chunks_per_block * 64);
  for (int c = 0; c < chunks_per_block; ++c) {
    const int k0 = k_base + c * 64;
    const float4* Kg4 = (const float4*)(K + ((size_t)(b * LSEQ) + k0 + r) * D_MODEL + h * EDIM);
    const float4* Vg4 = (const float4*)(V + ((size_t)(b * LSEQ) + k0 + r) * D_MODEL + h * EDIM);
#pragma unroll
    for (int i = 0; i < 4; ++i) {
      const int f4 = cg + 4 * i;
      float4 kv = Kg4[f4];
      float4 vv = Vg4[f4];
      ushort4 hh, ll;
      split2(kv.x, hh.x, ll.x);
      split2(kv.y, hh.y, ll.y);
      split2(kv.z, hh.z, ll.z);
      split2(kv.w, hh.w, ll.w);
      *(ushort4*)&KhS[r * 72 + f4 * 4] = hh;
      *(ushort4*)&KlS[r * 72 + f4 * 4] = ll;
      *(float4*)&VsS[r * 68 + f4 * 4] = vv;
    }
    __syncthreads();

    // ---- S^T = K . Q^T via MFMA (3-term split) ----
    f32x4 acc[4];
#pragma unroll
    for (int mt = 0; mt < 4; ++mt) acc[mt] = (f32x4){0.f, 0.f, 0.f, 0.f};
#pragma unroll
    for (int mt = 0; mt < 4; ++mt) {
      short8 kh = *(const short8*)&KhS[(mt * 16 + fr) * 72 + quad * 8];
      short8 kl = *(const short8*)&KlS[(mt * 16 + fr) * 72 + quad * 8];
      acc[mt] = __builtin_amdgcn_mfma_f32_16x16x32_bf16(kh, qh0, acc[mt], 0, 0, 0);
      acc[mt] = __builtin_amdgcn_mfma_f32_16x16x32_bf16(kh, ql0, acc[mt], 0, 0, 0);
      acc[mt] = __builtin_amdgcn_mfma_f32_16x16x32_bf16(kl, qh0, acc[mt], 0, 0, 0);
    }
#pragma unroll
    for (int mt = 0; mt < 4; ++mt) {
      short8 kh = *(const short8*)&KhS[(mt * 16 + fr) * 72 + 32 + quad * 8];
      short8 kl = *(const short8*)&KlS[(mt * 16 + fr) * 72 + 32 + quad * 8];
      acc[mt] = __builtin_amdgcn_mfma_f32_16x16x32_bf16(kh, qh1, acc[mt], 0, 0, 0);
      acc[mt] = __builtin_amdgcn_mfma_f32_16x16x32_bf16(kh, ql1, acc[mt], 0, 0, 0);
      acc[mt] = __builtin_amdgcn_mfma_f32_16x16x32_bf16(kl, qh1, acc[mt], 0, 0, 0);
    }

    // ---- softmax over this 64-key tile (per q = lane&15) ----
    float cm = -3.4e38f;
#pragma unroll
    for (int mt = 0; mt < 4; ++mt) {
#pragma unroll
      for (int rr = 0; rr < 4; ++rr) {
        float s = acc[mt][rr] * 0.125f;
        acc[mt][rr] = s;
        cm = fmaxf(cm, s);
      }
    }
    cm = fmaxf(cm, __shfl_xor(cm, 16, 64));
    cm = fmaxf(cm, __shfl_xor(cm, 32, 64));
    float mn = fmaxf(m, cm);
    if (mn > m) {
      float f = __expf(m - mn);
      l *= f;
#pragma unroll
      for (int i = 0; i < 16; ++i) {
        c4[i].x *= f; c4[i].y *= f; c4[i].z *= f; c4[i].w *= f;
      }
      m = mn;
    }
    float psum = 0.0f;
#pragma unroll
    for (int mt = 0; mt < 4; ++mt) {
#pragma unroll
      for (int rr = 0; rr < 4; ++rr) {
        float p = __expf(acc[mt][rr] - m);
        acc[mt][rr] = p;
        psum += p;
      }
    }
    l += psum;

    // ---- PV in fp32 VALU: each lane does its 16 keys x 64 dims ----
#pragma unroll
    for (int mt = 0; mt < 4; ++mt) {
#pragma unroll
      for (int rr = 0; rr < 4; ++rr) {
        const int krow = mt * 16 + quad * 4 + rr;
        const float4* vr = (const float4*)&VsS[krow * 68];
        const float p = acc[mt][rr];
#pragma unroll
        for (int i = 0; i < 16; ++i) {
          float4 vv = vr[i];
          c4[i].x += p * vv.x; c4[i].y += p * vv.y;
          c4[i].z += p * vv.z; c4[i].w += p * vv.w;
        }
      }
    }
    __syncthreads();
  }

  // ---- reduce partial ctx and l over the 4 quads (same q) ----
#pragma unroll
  for (int i = 0; i < 16; ++i) {
    c4[i].x += __shfl_xor(c4[i].x, 16, 64);
    c4[i].y += __shfl_xor(c4[i].y, 16, 64);
    c4[i].z += __shfl_xor(c4[i].z, 16, 64);
    c4[i].w += __shfl_xor(c4[i].w, 16, 64);
    c4[i].x += __shfl_xor(c4[i].x, 32, 64);
    c4[i].y += __shfl_xor(c4[i].y, 32, 64);
    c4[i].z += __shfl_xor(c4[i].z, 32, 64);
    c4[i].w += __shfl_xor(c4[i].w, 32, 64);
  }
  l += __shfl_xor(l, 16, 64);
  l += __shfl_xor(l, 32, 64);

  if (quad == 0 && qi < U) {
    part_m[(size_t)(bh * nsplit + split) * 64 + qi] = m;
    part_l[(size_t)(bh * nsplit + split) * 64 + qi] = l;
  }
  float* pc = part_ctx + (size_t)(bh * nsplit + split) * 4096;
  // e-major [e][q]: each quad writes its 16 dims (static reg indices)
  if (quad == 0) {
#pragma unroll
    for (int ii = 0; ii < 16; ++ii) pc[ii * 64 + qi] = (&c4[ii >> 2].x)[ii & 3];
  } else if (quad == 1) {
#pragma unroll
    for (int ii = 0; ii < 16; ++ii) pc[(16 + ii) * 64 + qi] = (&c4[4 + (ii >> 2)].x)[ii & 3];
  } else if (quad == 2) {
#pragma unroll
    for (int ii = 0; ii < 16; ++ii) pc[(32 + ii) * 64 + qi] = (&c4[8 + (ii >> 2)].x)[ii & 3];
  } else {
#pragma unroll
    for (int ii = 0; ii < 16; ++ii) pc[(48 + ii) * 64 + qi] = (&c4[12 + (ii >> 2)].x)[ii & 3];
  }
}

// =================== combine key-split flash partials ======================
__global__ __launch_bounds__(256) void attn_combine(
    const float* __restrict__ part_ctx, const float* __restrict__ part_m,
    const float* __restrict__ part_l, float* __restrict__ ctxTop,
    int U, int nsplit) {
  __shared__ float F[16][64];
  const int bh = blockIdx.x;
  const int t = threadIdx.x, lane = t & 63, grp = t >> 6;
  if (grp == 0) {
    float M = -3.4e38f;
    for (int s = 0; s < nsplit; ++s)
      M = fmaxf(M, part_m[(size_t)(bh * nsplit + s) * 64 + lane]);
    float L = 0.0f;
    for (int s = 0; s < nsplit; ++s)
      L += part_l[(size_t)(bh * nsplit + s) * 64 + lane] *
           __expf(part_m[(size_t)(bh * nsplit + s) * 64 + lane] - M);
    float invL = 1.0f / L;
    for (int s = 0; s < nsplit; ++s)
      F[s][lane] = __expf(part_m[(size_t)(bh * nsplit + s) * 64 + lane] - M) * invL;
  }
  __syncthreads();
  for (int ei = 0; ei < 16; ++ei) {
    int e = grp * 16 + ei;
    float acc = 0.0f;
    for (int s = 0; s < nsplit; ++s)
      acc += F[s][lane] * part_ctx[(size_t)(bh * nsplit + s) * 4096 + e * 64 + lane];
    if (lane < U) ctxTop[((size_t)bh * U + lane) * 64 + e] = acc;
  }
}

// ====================== V.mean over keys per (b,h) =========================
__global__ __launch_bounds__(256) void vmean_kernel(
    const float* __restrict__ V, float* __restrict__ Vm) {
  __shared__ float part[4][EDIM];
  int bh = blockIdx.x;
  int h = bh & (NHEADS - 1), b = bh >> 3;
  int t = threadIdx.x;
  int e = t & 63, c = t >> 6;
  float s = 0.0f;
  for (int k = c * (LSEQ / 4); k < (c + 1) * (LSEQ / 4); ++k)
    s += V[((size_t)b * LSEQ + k) * D_MODEL + h * EDIM + e];
  part[c][e] = s;
  __syncthreads();
  if (c == 0)
    Vm[(size_t)bh * EDIM + e] =
        (part[0][e] + part[1][e] + part[2][e] + part[3][e]) * (1.0f / (float)LSEQ);
}

// ============ base_out[b] = concat_h(Vmean[b,h]) @ W_out + b_out ===========
__global__ __launch_bounds__(256) void base_out_kernel(
    const float* __restrict__ Vm, const float* __restrict__ Wout,
    const float* __restrict__ bout, float* __restrict__ base) {
  __shared__ float cb[D_MODEL];
  int b = blockIdx.x;
  int t = threadIdx.x;
  for (int d = t; d < D_MODEL; d += 256) cb[d] = Vm[(size_t)b * D_MODEL + d];
  __syncthreads();
  for (int n = t; n < D_MODEL; n += 256) {
    float s = bout[n];
    for (int d = 0; d < D_MODEL; ++d) s += cb[d] * Wout[(size_t)d * D_MODEL + n];
    base[(size_t)b * D_MODEL + n] = s;
  }
}

// ================== broadcast base row into all output rows ================
__global__ __launch_bounds__(256) void fill_out(
    const float* __restrict__ base, float* __restrict__ out) {
  size_t i = (size_t)blockIdx.x * 256 + threadIdx.x;
  int n4 = (int)(i & 127);
  size_t bq = i >> 7;
  int b = (int)(bq >> 12);
  float4 v = ((const float4*)base)[(size_t)b * 128 + n4];
  ((float4*)out)[i] = v;
}

// ====== add (ctxTop - Vmean) @ W_out[h-slice] into the top rows ============
__global__ __launch_bounds__(256) void delta_out(
    const float* __restrict__ ctxTop, const float* __restrict__ Vm,
    const int* __restrict__ Mtop, const float* __restrict__ Wout,
    float* __restrict__ out, int U) {
  __shared__ float dlt[EDIM];
  int blk = blockIdx.x;
  int u = blk % U, bh = blk / U;
  int h = bh & (NHEADS - 1), b = bh >> 3;
  int q = Mtop[(size_t)bh * U + u];
  int t = threadIdx.x;
  if (t < EDIM)
    dlt[t] = ctxTop[((size_t)bh * U + u) * EDIM + t] - Vm[(size_t)bh * EDIM + t];
  __syncthreads();
  float* orow = out + ((size_t)b * LSEQ + q) * D_MODEL;
  for (int n = t; n < D_MODEL; n += 256) {
    float s = 0.0f;
#pragma unroll
    for (int e = 0; e < EDIM; ++e) s += dlt[e] * Wout[(size_t)(h * EDIM + e) * D_MODEL + n];
    atomicAdd(&orow[n], s);
  }
}

// ===========================================================================
extern "C" void kernel_launch(void* const* d_in, const int* in_sizes, int n_in,
                              void* d_out, int out_size, void* d_ws, size_t ws_size,
                              hipStream_t stream) {
  const float* query  = (const float*)d_in[0];
  const float* key_in = (const float*)d_in[1];
  const float* value  = (const float*)d_in[2];
  const float* W_Q    = (const float*)d_in[3];
  const float* W_K    = (const float*)d_in[4];
  const float* W_V    = (const float*)d_in[5];
  const float* W_out  = (const float*)d_in[6];
  const float* b_out  = (const float*)d_in[7];
  const int*   sidx   = (const int*)d_in[8];
  float* out = (float*)d_out;

  const int S = in_sizes[8] / LSEQ;   // 41
  const int U = S;

  char* ws = (char*)d_ws;
  size_t o = 0;
  float* Qf     = (float*)(ws + o); o += (size_t)BATCH * LSEQ * D_MODEL * 4;
  float* Kf     = (float*)(ws + o); o += (size_t)BATCH * LSEQ * D_MODEL * 4;
  float* Vf     = (float*)(ws + o); o += (size_t)BATCH * LSEQ * D_MODEL * 4;
  int*   Mtop   = (int*)  (ws + o); o += ((size_t)64 * U * 4 + 255) & ~255ULL;
  float* ctxTop = (float*)(ws + o); o += ((size_t)64 * U * EDIM * 4 + 255) & ~255ULL;
  float* Vm     = (float*)(ws + o); o += 16384;
  float* baseO  = (float*)(ws + o); o += 16384;
  u16*   Wpl    = (u16*)  (ws + o); o += (size_t)3 * 524288 * 2;   // 3 MB
  size_t unionOff = o;   // X planes / M / flash partials (disjoint lifetimes)

  // adaptive M-chunking so the 2 split planes fit
  int nchunk = 1;
  while (nchunk < 16 &&
         unionOff + 2 * ((size_t)(32768 / nchunk) * 512 * 2) > ws_size)
    nchunk <<= 1;
  const int Mchunk = 32768 / nchunk;
  u16* planes = (u16*)(ws + unionOff);
  const int planeStride = Mchunk * 512;

  float* M = (float*)(ws + unionOff);            // 1 MB, after gemms
  int nsplit = 16;
  for (;;) {
    size_t need = unionOff + 2 * ((size_t)64 * nsplit * 64 * 4)
                  + (size_t)64 * nsplit * 4096 * 4;
    if (need <= ws_size || nsplit == 1) break;
    nsplit >>= 1;
  }
  float* part_m   = (float*)(ws + unionOff);
  float* part_l   = part_m + (size_t)64 * nsplit * 64;
  float* part_ctx = part_l + (size_t)64 * nsplit * 64;
  const int chunks_per_block = 64 / nsplit;

  // ---- projections via split-bf16 MFMA (fused 3-term, single K-sweep) ----
  cvt_w<<<dim3(8, 8, 3), 256, 0, stream>>>(W_Q, W_K, W_V, Wpl);
  const float* Xsrc[3] = {query, key_in, value};
  float* Ydst[3] = {Qf, Kf, Vf};
  for (int g = 0; g < 3; ++g) {
    for (int c = 0; c < nchunk; ++c) {
      const float* xc = Xsrc[g] + (size_t)c * Mchunk * 512;
      float* yc = Ydst[g] + (size_t)c * Mchunk * 512;
      cvt_x<<<(Mchunk * 512) / 1024, 256, 0, stream>>>(xc, planes, planeStride);
      gemm_mfma<<<dim3(Mchunk / 128, 4), 256, 0, stream>>>(
          planes, planeStride, Wpl + (size_t)g * 524288, yc);
    }
  }

  qk_sample_half<<<(BATCH * LSEQ) / 4, 256, 0, stream>>>(Qf, Kf, sidx, M, S, 0);
  qk_sample_half<<<(BATCH * LSEQ) / 4, 256, 0, stream>>>(Qf, Kf, sidx, M, S, 1);
  topk_kernel<<<BATCH * NHEADS, 256, 0, stream>>>(M, Mtop, U);
  attn_flash<<<dim3(nsplit, BATCH * NHEADS), 256, 0, stream>>>(
      Qf, Kf, Vf, Mtop, part_ctx, part_m, part_l, U, nsplit, chunks_per_block);
  attn_combine<<<BATCH * NHEADS, 256, 0, stream>>>(
      part_ctx, part_m, part_l, ctxTop, U, nsplit);
  vmean_kernel<<<BATCH * NHEADS, 256, 0, stream>>>(Vf, Vm);
  base_out_kernel<<<BATCH, 256, 0, stream>>>(Vm, W_out, b_out, baseO);
  fill_out<<<(BATCH * LSEQ * (D_MODEL / 4)) / 256, 256, 0, stream>>>(baseO, out);
  delta_out<<<BATCH * NHEADS * U, 256, 0, stream>>>(ctxTop, Vm, Mtop, W_out, out, U);
}

// Round 3
// 918.632 us; speedup vs baseline: 1.2843x; 1.0868x over previous
//
#include <hip/hip_runtime.h>
#include <cstdint>
#include <cstddef>

#define D_MODEL 512
#define NHEADS  8
#define EDIM    64
#define BATCH   8
#define LSEQ    4096

typedef unsigned short u16;
typedef __attribute__((ext_vector_type(8))) short short8;
typedef __attribute__((ext_vector_type(4))) float f32x4;

// ===================== fp32 -> 2-term bf16 split ===========================
__device__ __forceinline__ u16 bf16_rne(float x) {
  unsigned int u = __float_as_uint(x);
  u += 0x7FFFu + ((u >> 16) & 1u);
  return (u16)(u >> 16);
}
__device__ __forceinline__ void split2(float x, u16& h, u16& l) {
  h = bf16_rne(x);
  float hf = __uint_as_float((unsigned int)h << 16);
  l = bf16_rne(x - hf);
}

// X (fp32, Mchunk x 512) -> 2 bf16 planes (h, l)
__global__ __launch_bounds__(256) void cvt_x(
    const float* __restrict__ X, u16* __restrict__ P, int planeStride) {
  size_t i = ((size_t)blockIdx.x * 256 + threadIdx.x) * 4;
  float4 x = *(const float4*)(X + i);
  ushort4 h, l;
  split2(x.x, h.x, l.x);
  split2(x.y, h.y, l.y);
  split2(x.z, h.z, l.z);
  split2(x.w, h.w, l.w);
  *(ushort4*)(P + i) = h;
  *(ushort4*)(P + planeStride + i) = l;
}

// W (512x512 fp32, k-major) -> transposed planes WT[n][k] (h,l), 3 weights
__global__ __launch_bounds__(256) void cvt_w(
    const float* __restrict__ W0, const float* __restrict__ W1,
    const float* __restrict__ W2, u16* __restrict__ out) {
  const float* W = (blockIdx.z == 0) ? W0 : ((blockIdx.z == 1) ? W1 : W2);
  u16* P = out + (size_t)blockIdx.z * 524288;       // 2 planes of 262144
  __shared__ float tile[64][65];
  const int k0 = blockIdx.x * 64, n0 = blockIdx.y * 64;
  const int t = threadIdx.x;
  const int tr = t >> 4, tc = (t & 15) * 4;
#pragma unroll
  for (int j = 0; j < 4; ++j) {
    int kr = tr + j * 16;
    float4 v = *(const float4*)(W + (size_t)(k0 + kr) * 512 + n0 + tc);
    tile[kr][tc + 0] = v.x; tile[kr][tc + 1] = v.y;
    tile[kr][tc + 2] = v.z; tile[kr][tc + 3] = v.w;
  }
  __syncthreads();
#pragma unroll
  for (int j = 0; j < 4; ++j) {
    int nr = tr + j * 16;
    ushort4 h, l;
    split2(tile[tc + 0][nr], h.x, l.x);
    split2(tile[tc + 1][nr], h.y, l.y);
    split2(tile[tc + 2][nr], h.z, l.z);
    split2(tile[tc + 3][nr], h.w, l.w);
    size_t off = (size_t)(n0 + nr) * 512 + k0 + tc;
    *(ushort4*)(P + off) = h;
    *(ushort4*)(P + 262144 + off) = l;
  }
}

__device__ __forceinline__ void gld_lds16(const char* g, char* l) {
  __builtin_amdgcn_global_load_lds((const __attribute__((address_space(1))) void*)g,
                                   (__attribute__((address_space(3))) void*)l, 16, 0, 0);
}

// ========== split-bf16 MFMA GEMM: Y = X @ W ================================
// 128x128 tile, BK=32, 4 waves. Fused 3-term split per k-step:
// acc += Ah*Bh + Ah*Bl + Al*Bh  (drops XlWl ~ 2^-18 rel).
__global__ __launch_bounds__(256, 2) void gemm_mfma(
    const u16* __restrict__ XP, int xPlaneStride,
    const u16* __restrict__ WP, float* __restrict__ Y) {
  __shared__ u16 Ah[128 * 32];
  __shared__ u16 Al[128 * 32];
  __shared__ u16 Bh[128 * 32];
  __shared__ u16 Bl[128 * 32];
  const int tid = threadIdx.x;
  const int lane = tid & 63, wv = tid >> 6;
  const int wm = (wv & 1) * 64, wn = (wv >> 1) * 64;
  const int bm = blockIdx.x * 128, bn = blockIdx.y * 128;
  const int fr = lane & 15, quad = lane >> 4;
  const int sRow = tid >> 2, sColB = (tid & 3) * 16;

  f32x4 acc[16];
#pragma unroll
  for (int i = 0; i < 16; ++i) acc[i] = (f32x4){0.f, 0.f, 0.f, 0.f};

  const u16* Xh = XP;
  const u16* Xl = XP + xPlaneStride;
  const u16* Wh = WP;
  const u16* Wl = WP + 262144;

  for (int kk = 0; kk < 16; ++kk) {
#pragma unroll
    for (int j = 0; j < 2; ++j) {
      const size_t rA = (size_t)(bm + j * 64 + sRow) * 512 + kk * 32;
      const size_t rB = (size_t)(bn + j * 64 + sRow) * 512 + kk * 32;
      const int lo = (j * 256 + wv * 64) * 16;
      gld_lds16((const char*)(Xh + rA) + sColB, (char*)Ah + lo);
      gld_lds16((const char*)(Xl + rA) + sColB, (char*)Al + lo);
      gld_lds16((const char*)(Wh + rB) + sColB, (char*)Bh + lo);
      gld_lds16((const char*)(Wl + rB) + sColB, (char*)Bl + lo);
    }
    __syncthreads();
    short8 ah[4], al[4], bh[4], bl[4];
#pragma unroll
    for (int mi = 0; mi < 4; ++mi) {
      ah[mi] = *(const short8*)&Ah[(wm + mi * 16 + fr) * 32 + quad * 8];
      al[mi] = *(const short8*)&Al[(wm + mi * 16 + fr) * 32 + quad * 8];
    }
#pragma unroll
    for (int ni = 0; ni < 4; ++ni) {
      bh[ni] = *(const short8*)&Bh[(wn + ni * 16 + fr) * 32 + quad * 8];
      bl[ni] = *(const short8*)&Bl[(wn + ni * 16 + fr) * 32 + quad * 8];
    }
#pragma unroll
    for (int mi = 0; mi < 4; ++mi)
#pragma unroll
      for (int ni = 0; ni < 4; ++ni)
        acc[mi * 4 + ni] = __builtin_amdgcn_mfma_f32_16x16x32_bf16(
            ah[mi], bh[ni], acc[mi * 4 + ni], 0, 0, 0);
#pragma unroll
    for (int mi = 0; mi < 4; ++mi)
#pragma unroll
      for (int ni = 0; ni < 4; ++ni)
        acc[mi * 4 + ni] = __builtin_amdgcn_mfma_f32_16x16x32_bf16(
            ah[mi], bl[ni], acc[mi * 4 + ni], 0, 0, 0);
#pragma unroll
    for (int mi = 0; mi < 4; ++mi)
#pragma unroll
      for (int ni = 0; ni < 4; ++ni)
        acc[mi * 4 + ni] = __builtin_amdgcn_mfma_f32_16x16x32_bf16(
            al[mi], bh[ni], acc[mi * 4 + ni], 0, 0, 0);
    __syncthreads();
  }
#pragma unroll
  for (int mi = 0; mi < 4; ++mi)
#pragma unroll
    for (int ni = 0; ni < 4; ++ni) {
      const f32x4 a = acc[mi * 4 + ni];
      float* yp = Y + (size_t)(bm + wm + mi * 16 + quad * 4) * 512 + (bn + wn + ni * 16 + fr);
#pragma unroll
      for (int r = 0; r < 4; ++r) yp[(size_t)r * 512] = a[r];
    }
}

// ================= QK_sample -> M, half-row per pass =======================
// Restructured for latency: 8-lane dot groups, 2 samples per iteration,
// lane = (sample-parity s)*32 + head*8 + dim-octet. 3 shuffles / 2 samples
// (was 4 / 1), 4-sample-deep prefetch (was 1). Same bytes, same coalescing
// (each half-wave reads a contiguous 1KB row segment).
__global__ __launch_bounds__(256) void qk_sample_half(
    const float* __restrict__ Q, const float* __restrict__ K,
    const int* __restrict__ sidx, float* __restrict__ M, int S, int hg) {
  const int blk = blockIdx.x;
  const int lane = threadIdx.x & 63;
  const int b = blk & 7;                      // XCD swizzle: batch <-> XCD
  const int q = ((blk >> 3) << 2) + (threadIdx.x >> 6);
  const int s = lane >> 5;                    // sample parity
  const int hl = (lane >> 3) & 3;             // head within group
  const int d = lane & 7;                     // dim octet
  const int h = hg * 4 + hl;
  const int col = hg * 256 + hl * 64 + d * 8;

  const float* Qp = Q + ((size_t)b * LSEQ + q) * D_MODEL + col;
  const float4 q0 = *(const float4*)Qp;
  const float4 q1 = *(const float4*)(Qp + 4);
  const float* Kb = K + (size_t)b * LSEQ * D_MODEL + col;
  const int* sp = sidx + (size_t)q * S;

  // row pointer for iteration-start j (this lane handles sample j+s, clamped)
  auto rowp = [&](int j) -> const float* {
    int jj = j + s;
    int row = sp[(jj < S) ? jj : (S - 1)];
    return Kb + (size_t)row * D_MODEL;
  };

  // prefetch 2 iterations (4 samples) deep
  const float* pr0 = rowp(0);
  float4 a0 = *(const float4*)pr0, b0 = *(const float4*)(pr0 + 4);
  const float* pr1 = rowp(2);
  float4 a1 = *(const float4*)pr1, b1 = *(const float4*)(pr1 + 4);

  float mx = -3.4e38f, sum = 0.0f;
  for (int j = 0; j < S; j += 2) {
    const float4 ca = a0, cb = b0;
    a0 = a1; b0 = b1;
    const float* pn = rowp(j + 4);
    a1 = *(const float4*)pn;
    b1 = *(const float4*)(pn + 4);
    float p = ca.x * q0.x + ca.y * q0.y + ca.z * q0.z + ca.w * q0.w +
              cb.x * q1.x + cb.y * q1.y + cb.z * q1.z + cb.w * q1.w;
    p += __shfl_xor(p, 1, 64);
    p += __shfl_xor(p, 2, 64);
    p += __shfl_xor(p, 4, 64);   // 8-lane group done: full 64-dim... (x2 halves via q0/q1 both held)
    if (j + s < S) {
      mx = fmaxf(mx, p);
      sum += p;
    }
  }
  // combine the two sample-parity halves (same q, same head)
  mx = fmaxf(mx, __shfl_xor(mx, 32, 64));
  sum += __shfl_xor(sum, 32, 64);
  if (s == 0 && d == 0)
    M[((size_t)(b * NHEADS + h)) * LSEQ + q] = mx - sum / (float)S;
}

// ===================== top-U indices per (b,h) =============================
__global__ __launch_bounds__(256) void topk_kernel(
    const float* __restrict__ M, int* __restrict__ Mtop, int U) {
  __shared__ float vals[LSEQ];
  __shared__ float rmax[256];
  __shared__ int ridx[256];
  int bh = blockIdx.x;
  int t = threadIdx.x;
  for (int i = t; i < LSEQ; i += 256) vals[i] = M[(size_t)bh * LSEQ + i];
  __syncthreads();
  for (int it = 0; it < U; ++it) {
    float best = -3.4e38f; int bi = -1;
    for (int i = t; i < LSEQ; i += 256) {
      float v = vals[i];
      if (v > best) { best = v; bi = i; }
    }
    rmax[t] = best; ridx[t] = bi;
    __syncthreads();
    for (int s = 128; s > 0; s >>= 1) {
      if (t < s) {
        if (rmax[t + s] > rmax[t]) { rmax[t] = rmax[t + s]; ridx[t] = ridx[t + s]; }
      }
      __syncthreads();
    }
    if (t == 0) {
      Mtop[(size_t)bh * U + it] = ridx[0];
      vals[ridx[0]] = -3.4e38f;
    }
    __syncthreads();
  }
}

// ============== flash attention over top-U rows, key-split =================
// MFMA QK^T (swapped: S^T = mfma(K, Q)) + fp32 VALU PV.
__global__ __launch_bounds__(256, 2) void attn_flash(
    const float* __restrict__ Q, const float* __restrict__ K,
    const float* __restrict__ V, const int* __restrict__ Mtop,
    float* __restrict__ part_ctx, float* __restrict__ part_m,
    float* __restrict__ part_l, int U, int nsplit, int chunks_per_block) {
  __shared__ u16 KhS[64 * 72];
  __shared__ u16 KlS[64 * 72];
  __shared__ float VsS[64 * 68];
  const int bh = blockIdx.y, split = blockIdx.x;
  const int h = bh & (NHEADS - 1), b = bh >> 3;
  const int t = threadIdx.x, w = t >> 6, lane = t & 63;
  const int fr = lane & 15, quad = lane >> 4;

  // ---- Q fragments (per lane: q-row = Mtop[w*16+fr], dims quad*8..+8, +32)
  const int qi = w * 16 + fr;
  const int qrow = (qi < U) ? Mtop[(size_t)bh * U + qi] : Mtop[(size_t)bh * U];
  const float4* Qr = (const float4*)(Q + ((size_t)(b * LSEQ) + qrow) * D_MODEL + h * EDIM);
  float4 qa = Qr[quad * 2], qb = Qr[quad * 2 + 1];
  float4 qc = Qr[quad * 2 + 8], qd = Qr[quad * 2 + 9];
  short8 qh0, ql0, qh1, ql1;
  {
    u16 hh, ll;
    split2(qa.x, hh, ll); qh0[0] = (short)hh; ql0[0] = (short)ll;
    split2(qa.y, hh, ll); qh0[1] = (short)hh; ql0[1] = (short)ll;
    split2(qa.z, hh, ll); qh0[2] = (short)hh; ql0[2] = (short)ll;
    split2(qa.w, hh, ll); qh0[3] = (short)hh; ql0[3] = (short)ll;
    split2(qb.x, hh, ll); qh0[4] = (short)hh; ql0[4] = (short)ll;
    split2(qb.y, hh, ll); qh0[5] = (short)hh; ql0[5] = (short)ll;
    split2(qb.z, hh, ll); qh0[6] = (short)hh; ql0[6] = (short)ll;
    split2(qb.w, hh, ll); qh0[7] = (short)hh; ql0[7] = (short)ll;
    split2(qc.x, hh, ll); qh1[0] = (short)hh; ql1[0] = (short)ll;
    split2(qc.y, hh, ll); qh1[1] = (short)hh; ql1[1] = (short)ll;
    split2(qc.z, hh, ll); qh1[2] = (short)hh; ql1[2] = (short)ll;
    split2(qc.w, hh, ll); qh1[3] = (short)hh; ql1[3] = (short)ll;
    split2(qd.x, hh, ll); qh1[4] = (short)hh; ql1[4] = (short)ll;
    split2(qd.y, hh, ll); qh1[5] = (short)hh; ql1[5] = (short)ll;
    split2(qd.z, hh, ll); qh1[6] = (short)hh; ql1[6] = (short)ll;
    split2(qd.w, hh, ll); qh1[7] = (short)hh; ql1[7] = (short)ll;
  }

  float4 c4[16];
#pragma unroll
  for (int i = 0; i < 16; ++i) c4[i] = make_float4(0.f, 0.f, 0.f, 0.f);
  float m = -1e30f, l = 0.0f;

  // staging coords: thread covers key-row r, float4s (cg + 4*i)
  const int r = t >> 2, cg = t & 3;

  const int k_base = split * (chunks_per_block * 64);
  for (int c = 0; c < chunks_per_block; ++c) {
    const int k0 = k_base + c * 64;
    const float4* Kg4 = (const float4*)(K + ((size_t)(b * LSEQ) + k0 + r) * D_MODEL + h * EDIM);
    const float4* Vg4 = (const float4*)(V + ((size_t)(b * LSEQ) + k0 + r) * D_MODEL + h * EDIM);
#pragma unroll
    for (int i = 0; i < 4; ++i) {
      const int f4 = cg + 4 * i;
      float4 kv = Kg4[f4];
      float4 vv = Vg4[f4];
      ushort4 hh, ll;
      split2(kv.x, hh.x, ll.x);
      split2(kv.y, hh.y, ll.y);
      split2(kv.z, hh.z, ll.z);
      split2(kv.w, hh.w, ll.w);
      *(ushort4*)&KhS[r * 72 + f4 * 4] = hh;
      *(ushort4*)&KlS[r * 72 + f4 * 4] = ll;
      *(float4*)&VsS[r * 68 + f4 * 4] = vv;
    }
    __syncthreads();

    // ---- S^T = K . Q^T via MFMA (3-term split) ----
    f32x4 acc[4];
#pragma unroll
    for (int mt = 0; mt < 4; ++mt) acc[mt] = (f32x4){0.f, 0.f, 0.f, 0.f};
#pragma unroll
    for (int mt = 0; mt < 4; ++mt) {
      short8 kh = *(const short8*)&KhS[(mt * 16 + fr) * 72 + quad * 8];
      short8 kl = *(const short8*)&KlS[(mt * 16 + fr) * 72 + quad * 8];
      acc[mt] = __builtin_amdgcn_mfma_f32_16x16x32_bf16(kh, qh0, acc[mt], 0, 0, 0);
      acc[mt] = __builtin_amdgcn_mfma_f32_16x16x32_bf16(kh, ql0, acc[mt], 0, 0, 0);
      acc[mt] = __builtin_amdgcn_mfma_f32_16x16x32_bf16(kl, qh0, acc[mt], 0, 0, 0);
    }
#pragma unroll
    for (int mt = 0; mt < 4; ++mt) {
      short8 kh = *(const short8*)&KhS[(mt * 16 + fr) * 72 + 32 + quad * 8];
      short8 kl = *(const short8*)&KlS[(mt * 16 + fr) * 72 + 32 + quad * 8];
      acc[mt] = __builtin_amdgcn_mfma_f32_16x16x32_bf16(kh, qh1, acc[mt], 0, 0, 0);
      acc[mt] = __builtin_amdgcn_mfma_f32_16x16x32_bf16(kh, ql1, acc[mt], 0, 0, 0);
      acc[mt] = __builtin_amdgcn_mfma_f32_16x16x32_bf16(kl, qh1, acc[mt], 0, 0, 0);
    }

    // ---- softmax over this 64-key tile (per q = lane&15) ----
    float cm = -3.4e38f;
#pragma unroll
    for (int mt = 0; mt < 4; ++mt) {
#pragma unroll
      for (int rr = 0; rr < 4; ++rr) {
        float s = acc[mt][rr] * 0.125f;
        acc[mt][rr] = s;
        cm = fmaxf(cm, s);
      }
    }
    cm = fmaxf(cm, __shfl_xor(cm, 16, 64));
    cm = fmaxf(cm, __shfl_xor(cm, 32, 64));
    float mn = fmaxf(m, cm);
    if (mn > m) {
      float f = __expf(m - mn);
      l *= f;
#pragma unroll
      for (int i = 0; i < 16; ++i) {
        c4[i].x *= f; c4[i].y *= f; c4[i].z *= f; c4[i].w *= f;
      }
      m = mn;
    }
    float psum = 0.0f;
#pragma unroll
    for (int mt = 0; mt < 4; ++mt) {
#pragma unroll
      for (int rr = 0; rr < 4; ++rr) {
        float p = __expf(acc[mt][rr] - m);
        acc[mt][rr] = p;
        psum += p;
      }
    }
    l += psum;

    // ---- PV in fp32 VALU: each lane does its 16 keys x 64 dims ----
#pragma unroll
    for (int mt = 0; mt < 4; ++mt) {
#pragma unroll
      for (int rr = 0; rr < 4; ++rr) {
        const int krow = mt * 16 + quad * 4 + rr;
        const float4* vr = (const float4*)&VsS[krow * 68];
        const float p = acc[mt][rr];
#pragma unroll
        for (int i = 0; i < 16; ++i) {
          float4 vv = vr[i];
          c4[i].x += p * vv.x; c4[i].y += p * vv.y;
          c4[i].z += p * vv.z; c4[i].w += p * vv.w;
        }
      }
    }
    __syncthreads();
  }

  // ---- reduce partial ctx and l over the 4 quads (same q) ----
#pragma unroll
  for (int i = 0; i < 16; ++i) {
    c4[i].x += __shfl_xor(c4[i].x, 16, 64);
    c4[i].y += __shfl_xor(c4[i].y, 16, 64);
    c4[i].z += __shfl_xor(c4[i].z, 16, 64);
    c4[i].w += __shfl_xor(c4[i].w, 16, 64);
    c4[i].x += __shfl_xor(c4[i].x, 32, 64);
    c4[i].y += __shfl_xor(c4[i].y, 32, 64);
    c4[i].z += __shfl_xor(c4[i].z, 32, 64);
    c4[i].w += __shfl_xor(c4[i].w, 32, 64);
  }
  l += __shfl_xor(l, 16, 64);
  l += __shfl_xor(l, 32, 64);

  if (quad == 0 && qi < U) {
    part_m[(size_t)(bh * nsplit + split) * 64 + qi] = m;
    part_l[(size_t)(bh * nsplit + split) * 64 + qi] = l;
  }
  float* pc = part_ctx + (size_t)(bh * nsplit + split) * 4096;
  // e-major [e][q]: each quad writes its 16 dims (static reg indices)
  if (quad == 0) {
#pragma unroll
    for (int ii = 0; ii < 16; ++ii) pc[ii * 64 + qi] = (&c4[ii >> 2].x)[ii & 3];
  } else if (quad == 1) {
#pragma unroll
    for (int ii = 0; ii < 16; ++ii) pc[(16 + ii) * 64 + qi] = (&c4[4 + (ii >> 2)].x)[ii & 3];
  } else if (quad == 2) {
#pragma unroll
    for (int ii = 0; ii < 16; ++ii) pc[(32 + ii) * 64 + qi] = (&c4[8 + (ii >> 2)].x)[ii & 3];
  } else {
#pragma unroll
    for (int ii = 0; ii < 16; ++ii) pc[(48 + ii) * 64 + qi] = (&c4[12 + (ii >> 2)].x)[ii & 3];
  }
}

// =================== combine key-split flash partials ======================
__global__ __launch_bounds__(256) void attn_combine(
    const float* __restrict__ part_ctx, const float* __restrict__ part_m,
    const float* __restrict__ part_l, float* __restrict__ ctxTop,
    int U, int nsplit) {
  __shared__ float F[16][64];
  const int bh = blockIdx.x;
  const int t = threadIdx.x, lane = t & 63, grp = t >> 6;
  if (grp == 0) {
    float M = -3.4e38f;
    for (int s = 0; s < nsplit; ++s)
      M = fmaxf(M, part_m[(size_t)(bh * nsplit + s) * 64 + lane]);
    float L = 0.0f;
    for (int s = 0; s < nsplit; ++s)
      L += part_l[(size_t)(bh * nsplit + s) * 64 + lane] *
           __expf(part_m[(size_t)(bh * nsplit + s) * 64 + lane] - M);
    float invL = 1.0f / L;
    for (int s = 0; s < nsplit; ++s)
      F[s][lane] = __expf(part_m[(size_t)(bh * nsplit + s) * 64 + lane] - M) * invL;
  }
  __syncthreads();
  for (int ei = 0; ei < 16; ++ei) {
    int e = grp * 16 + ei;
    float acc = 0.0f;
    for (int s = 0; s < nsplit; ++s)
      acc += F[s][lane] * part_ctx[(size_t)(bh * nsplit + s) * 4096 + e * 64 + lane];
    if (lane < U) ctxTop[((size_t)bh * U + lane) * 64 + e] = acc;
  }
}

// ====================== V.mean over keys per (b,h) =========================
__global__ __launch_bounds__(256) void vmean_kernel(
    const float* __restrict__ V, float* __restrict__ Vm) {
  __shared__ float part[4][EDIM];
  int bh = blockIdx.x;
  int h = bh & (NHEADS - 1), b = bh >> 3;
  int t = threadIdx.x;
  int e = t & 63, c = t >> 6;
  float s = 0.0f;
  for (int k = c * (LSEQ / 4); k < (c + 1) * (LSEQ / 4); ++k)
    s += V[((size_t)b * LSEQ + k) * D_MODEL + h * EDIM + e];
  part[c][e] = s;
  __syncthreads();
  if (c == 0)
    Vm[(size_t)bh * EDIM + e] =
        (part[0][e] + part[1][e] + part[2][e] + part[3][e]) * (1.0f / (float)LSEQ);
}

// ============ base_out[b] = concat_h(Vmean[b,h]) @ W_out + b_out ===========
__global__ __launch_bounds__(256) void base_out_kernel(
    const float* __restrict__ Vm, const float* __restrict__ Wout,
    const float* __restrict__ bout, float* __restrict__ base) {
  __shared__ float cb[D_MODEL];
  int b = blockIdx.x;
  int t = threadIdx.x;
  for (int d = t; d < D_MODEL; d += 256) cb[d] = Vm[(size_t)b * D_MODEL + d];
  __syncthreads();
  for (int n = t; n < D_MODEL; n += 256) {
    float s = bout[n];
    for (int d = 0; d < D_MODEL; ++d) s += cb[d] * Wout[(size_t)d * D_MODEL + n];
    base[(size_t)b * D_MODEL + n] = s;
  }
}

// ================== broadcast base row into all output rows ================
__global__ __launch_bounds__(256) void fill_out(
    const float* __restrict__ base, float* __restrict__ out) {
  size_t i = (size_t)blockIdx.x * 256 + threadIdx.x;
  int n4 = (int)(i & 127);
  size_t bq = i >> 7;
  int b = (int)(bq >> 12);
  float4 v = ((const float4*)base)[(size_t)b * 128 + n4];
  ((float4*)out)[i] = v;
}

// ====== add (ctxTop - Vmean) @ W_out[h-slice] into the top rows ============
__global__ __launch_bounds__(256) void delta_out(
    const float* __restrict__ ctxTop, const float* __restrict__ Vm,
    const int* __restrict__ Mtop, const float* __restrict__ Wout,
    float* __restrict__ out, int U) {
  __shared__ float dlt[EDIM];
  int blk = blockIdx.x;
  int u = blk % U, bh = blk / U;
  int h = bh & (NHEADS - 1), b = bh >> 3;
  int q = Mtop[(size_t)bh * U + u];
  int t = threadIdx.x;
  if (t < EDIM)
    dlt[t] = ctxTop[((size_t)bh * U + u) * EDIM + t] - Vm[(size_t)bh * EDIM + t];
  __syncthreads();
  float* orow = out + ((size_t)b * LSEQ + q) * D_MODEL;
  for (int n = t; n < D_MODEL; n += 256) {
    float s = 0.0f;
#pragma unroll
    for (int e = 0; e < EDIM; ++e) s += dlt[e] * Wout[(size_t)(h * EDIM + e) * D_MODEL + n];
    atomicAdd(&orow[n], s);
  }
}

// ===========================================================================
extern "C" void kernel_launch(void* const* d_in, const int* in_sizes, int n_in,
                              void* d_out, int out_size, void* d_ws, size_t ws_size,
                              hipStream_t stream) {
  const float* query  = (const float*)d_in[0];
  const float* key_in = (const float*)d_in[1];
  const float* value  = (const float*)d_in[2];
  const float* W_Q    = (const float*)d_in[3];
  const float* W_K    = (const float*)d_in[4];
  const float* W_V    = (const float*)d_in[5];
  const float* W_out  = (const float*)d_in[6];
  const float* b_out  = (const float*)d_in[7];
  const int*   sidx   = (const int*)d_in[8];
  float* out = (float*)d_out;

  const int S = in_sizes[8] / LSEQ;   // 41
  const int U = S;

  char* ws = (char*)d_ws;
  size_t o = 0;
  float* Qf     = (float*)(ws + o); o += (size_t)BATCH * LSEQ * D_MODEL * 4;
  float* Kf     = (float*)(ws + o); o += (size_t)BATCH * LSEQ * D_MODEL * 4;
  float* Vf     = (float*)(ws + o); o += (size_t)BATCH * LSEQ * D_MODEL * 4;
  int*   Mtop   = (int*)  (ws + o); o += ((size_t)64 * U * 4 + 255) & ~255ULL;
  float* ctxTop = (float*)(ws + o); o += ((size_t)64 * U * EDIM * 4 + 255) & ~255ULL;
  float* Vm     = (float*)(ws + o); o += 16384;
  float* baseO  = (float*)(ws + o); o += 16384;
  u16*   Wpl    = (u16*)  (ws + o); o += (size_t)3 * 524288 * 2;   // 3 MB
  size_t unionOff = o;   // X planes / M / flash partials (disjoint lifetimes)

  // adaptive M-chunking so the 2 split planes fit
  int nchunk = 1;
  while (nchunk < 16 &&
         unionOff + 2 * ((size_t)(32768 / nchunk) * 512 * 2) > ws_size)
    nchunk <<= 1;
  const int Mchunk = 32768 / nchunk;
  u16* planes = (u16*)(ws + unionOff);
  const int planeStride = Mchunk * 512;

  float* M = (float*)(ws + unionOff);            // 1 MB, after gemms
  int nsplit = 16;
  for (;;) {
    size_t need = unionOff + 2 * ((size_t)64 * nsplit * 64 * 4)
                  + (size_t)64 * nsplit * 4096 * 4;
    if (need <= ws_size || nsplit == 1) break;
    nsplit >>= 1;
  }
  float* part_m   = (float*)(ws + unionOff);
  float* part_l   = part_m + (size_t)64 * nsplit * 64;
  float* part_ctx = part_l + (size_t)64 * nsplit * 64;
  const int chunks_per_block = 64 / nsplit;

  // ---- projections via split-bf16 MFMA (fused 3-term, single K-sweep) ----
  cvt_w<<<dim3(8, 8, 3), 256, 0, stream>>>(W_Q, W_K, W_V, Wpl);
  const float* Xsrc[3] = {query, key_in, value};
  float* Ydst[3] = {Qf, Kf, Vf};
  for (int g = 0; g < 3; ++g) {
    for (int c = 0; c < nchunk; ++c) {
      const float* xc = Xsrc[g] + (size_t)c * Mchunk * 512;
      float* yc = Ydst[g] + (size_t)c * Mchunk * 512;
      cvt_x<<<(Mchunk * 512) / 1024, 256, 0, stream>>>(xc, planes, planeStride);
      gemm_mfma<<<dim3(Mchunk / 128, 4), 256, 0, stream>>>(
          planes, planeStride, Wpl + (size_t)g * 524288, yc);
    }
  }

  qk_sample_half<<<(BATCH * LSEQ) / 4, 256, 0, stream>>>(Qf, Kf, sidx, M, S, 0);
  qk_sample_half<<<(BATCH * LSEQ) / 4, 256, 0, stream>>>(Qf, Kf, sidx, M, S, 1);
  topk_kernel<<<BATCH * NHEADS, 256, 0, stream>>>(M, Mtop, U);
  attn_flash<<<dim3(nsplit, BATCH * NHEADS), 256, 0, stream>>>(
      Qf, Kf, Vf, Mtop, part_ctx, part_m, part_l, U, nsplit, chunks_per_block);
  attn_combine<<<BATCH * NHEADS, 256, 0, stream>>>(
      part_ctx, part_m, part_l, ctxTop, U, nsplit);
  vmean_kernel<<<BATCH * NHEADS, 256, 0, stream>>>(Vf, Vm);
  base_out_kernel<<<BATCH, 256, 0, stream>>>(Vm, W_out, b_out, baseO);
  fill_out<<<(BATCH * LSEQ * (D_MODEL / 4)) / 256, 256, 0, stream>>>(baseO, out);
  delta_out<<<BATCH * NHEADS * U, 256, 0, stream>>>(ctxTop, Vm, Mtop, W_out, out, U);
}

// Round 4
// 842.963 us; speedup vs baseline: 1.3996x; 1.0898x over previous
//
#include <hip/hip_runtime.h>
#include <cstdint>
#include <cstddef>

#define D_MODEL 512
#define NHEADS  8
#define EDIM    64
#define BATCH   8
#define LSEQ    4096

typedef unsigned short u16;
typedef __attribute__((ext_vector_type(8))) short short8;
typedef __attribute__((ext_vector_type(4))) float f32x4;

// ===================== fp32 -> 2-term bf16 split ===========================
__device__ __forceinline__ u16 bf16_rne(float x) {
  unsigned int u = __float_as_uint(x);
  u += 0x7FFFu + ((u >> 16) & 1u);
  return (u16)(u >> 16);
}
__device__ __forceinline__ void split2(float x, u16& h, u16& l) {
  h = bf16_rne(x);
  float hf = __uint_as_float((unsigned int)h << 16);
  l = bf16_rne(x - hf);
}

// X (fp32, Mchunk x 512) -> 2 bf16 planes (h, l)
__global__ __launch_bounds__(256) void cvt_x(
    const float* __restrict__ X, u16* __restrict__ P, int planeStride) {
  size_t i = ((size_t)blockIdx.x * 256 + threadIdx.x) * 4;
  float4 x = *(const float4*)(X + i);
  ushort4 h, l;
  split2(x.x, h.x, l.x);
  split2(x.y, h.y, l.y);
  split2(x.z, h.z, l.z);
  split2(x.w, h.w, l.w);
  *(ushort4*)(P + i) = h;
  *(ushort4*)(P + planeStride + i) = l;
}

// W (512x512 fp32, k-major) -> transposed planes WT[n][k] (h,l), 4 weights
// (W_Q, W_K, W_V for the projections; W_out for the MFMA delta epilogue)
__global__ __launch_bounds__(256) void cvt_w(
    const float* __restrict__ W0, const float* __restrict__ W1,
    const float* __restrict__ W2, const float* __restrict__ W3,
    u16* __restrict__ out) {
  const float* W = (blockIdx.z == 0) ? W0 : ((blockIdx.z == 1) ? W1 :
                   ((blockIdx.z == 2) ? W2 : W3));
  u16* P = out + (size_t)blockIdx.z * 524288;       // 2 planes of 262144
  __shared__ float tile[64][65];
  const int k0 = blockIdx.x * 64, n0 = blockIdx.y * 64;
  const int t = threadIdx.x;
  const int tr = t >> 4, tc = (t & 15) * 4;
#pragma unroll
  for (int j = 0; j < 4; ++j) {
    int kr = tr + j * 16;
    float4 v = *(const float4*)(W + (size_t)(k0 + kr) * 512 + n0 + tc);
    tile[kr][tc + 0] = v.x; tile[kr][tc + 1] = v.y;
    tile[kr][tc + 2] = v.z; tile[kr][tc + 3] = v.w;
  }
  __syncthreads();
#pragma unroll
  for (int j = 0; j < 4; ++j) {
    int nr = tr + j * 16;
    ushort4 h, l;
    split2(tile[tc + 0][nr], h.x, l.x);
    split2(tile[tc + 1][nr], h.y, l.y);
    split2(tile[tc + 2][nr], h.z, l.z);
    split2(tile[tc + 3][nr], h.w, l.w);
    size_t off = (size_t)(n0 + nr) * 512 + k0 + tc;
    *(ushort4*)(P + off) = h;
    *(ushort4*)(P + 262144 + off) = l;
  }
}

__device__ __forceinline__ void gld_lds16(const char* g, char* l) {
  __builtin_amdgcn_global_load_lds((const __attribute__((address_space(1))) void*)g,
                                   (__attribute__((address_space(3))) void*)l, 16, 0, 0);
}

// ========== split-bf16 MFMA GEMM: Y = X @ W ================================
// 128x128 tile, BK=32, 4 waves. Fused 3-term split per k-step:
// acc += Ah*Bh + Ah*Bl + Al*Bh  (drops XlWl ~ 2^-18 rel).
__global__ __launch_bounds__(256, 2) void gemm_mfma(
    const u16* __restrict__ XP, int xPlaneStride,
    const u16* __restrict__ WP, float* __restrict__ Y) {
  __shared__ u16 Ah[128 * 32];
  __shared__ u16 Al[128 * 32];
  __shared__ u16 Bh[128 * 32];
  __shared__ u16 Bl[128 * 32];
  const int tid = threadIdx.x;
  const int lane = tid & 63, wv = tid >> 6;
  const int wm = (wv & 1) * 64, wn = (wv >> 1) * 64;
  const int bm = blockIdx.x * 128, bn = blockIdx.y * 128;
  const int fr = lane & 15, quad = lane >> 4;
  const int sRow = tid >> 2, sColB = (tid & 3) * 16;

  f32x4 acc[16];
#pragma unroll
  for (int i = 0; i < 16; ++i) acc[i] = (f32x4){0.f, 0.f, 0.f, 0.f};

  const u16* Xh = XP;
  const u16* Xl = XP + xPlaneStride;
  const u16* Wh = WP;
  const u16* Wl = WP + 262144;

  for (int kk = 0; kk < 16; ++kk) {
#pragma unroll
    for (int j = 0; j < 2; ++j) {
      const size_t rA = (size_t)(bm + j * 64 + sRow) * 512 + kk * 32;
      const size_t rB = (size_t)(bn + j * 64 + sRow) * 512 + kk * 32;
      const int lo = (j * 256 + wv * 64) * 16;
      gld_lds16((const char*)(Xh + rA) + sColB, (char*)Ah + lo);
      gld_lds16((const char*)(Xl + rA) + sColB, (char*)Al + lo);
      gld_lds16((const char*)(Wh + rB) + sColB, (char*)Bh + lo);
      gld_lds16((const char*)(Wl + rB) + sColB, (char*)Bl + lo);
    }
    __syncthreads();
    short8 ah[4], al[4], bh[4], bl[4];
#pragma unroll
    for (int mi = 0; mi < 4; ++mi) {
      ah[mi] = *(const short8*)&Ah[(wm + mi * 16 + fr) * 32 + quad * 8];
      al[mi] = *(const short8*)&Al[(wm + mi * 16 + fr) * 32 + quad * 8];
    }
#pragma unroll
    for (int ni = 0; ni < 4; ++ni) {
      bh[ni] = *(const short8*)&Bh[(wn + ni * 16 + fr) * 32 + quad * 8];
      bl[ni] = *(const short8*)&Bl[(wn + ni * 16 + fr) * 32 + quad * 8];
    }
#pragma unroll
    for (int mi = 0; mi < 4; ++mi)
#pragma unroll
      for (int ni = 0; ni < 4; ++ni)
        acc[mi * 4 + ni] = __builtin_amdgcn_mfma_f32_16x16x32_bf16(
            ah[mi], bh[ni], acc[mi * 4 + ni], 0, 0, 0);
#pragma unroll
    for (int mi = 0; mi < 4; ++mi)
#pragma unroll
      for (int ni = 0; ni < 4; ++ni)
        acc[mi * 4 + ni] = __builtin_amdgcn_mfma_f32_16x16x32_bf16(
            ah[mi], bl[ni], acc[mi * 4 + ni], 0, 0, 0);
#pragma unroll
    for (int mi = 0; mi < 4; ++mi)
#pragma unroll
      for (int ni = 0; ni < 4; ++ni)
        acc[mi * 4 + ni] = __builtin_amdgcn_mfma_f32_16x16x32_bf16(
            al[mi], bh[ni], acc[mi * 4 + ni], 0, 0, 0);
    __syncthreads();
  }
#pragma unroll
  for (int mi = 0; mi < 4; ++mi)
#pragma unroll
    for (int ni = 0; ni < 4; ++ni) {
      const f32x4 a = acc[mi * 4 + ni];
      float* yp = Y + (size_t)(bm + wm + mi * 16 + quad * 4) * 512 + (bn + wn + ni * 16 + fr);
#pragma unroll
      for (int r = 0; r < 4; ++r) yp[(size_t)r * 512] = a[r];
    }
}

// ================= QK_sample -> M, half-row per pass =======================
__global__ __launch_bounds__(256) void qk_sample_half(
    const float* __restrict__ Q, const float* __restrict__ K,
    const int* __restrict__ sidx, float* __restrict__ M, int S, int hg) {
  const int blk = blockIdx.x;
  const int lane = threadIdx.x & 63;
  const int b = blk & 7;                      // XCD swizzle: batch <-> XCD
  const int q = ((blk >> 3) << 2) + (threadIdx.x >> 6);
  const int s = lane >> 5;                    // sample parity
  const int hl = (lane >> 3) & 3;             // head within group
  const int d = lane & 7;                     // dim octet
  const int h = hg * 4 + hl;
  const int col = hg * 256 + hl * 64 + d * 8;

  const float* Qp = Q + ((size_t)b * LSEQ + q) * D_MODEL + col;
  const float4 q0 = *(const float4*)Qp;
  const float4 q1 = *(const float4*)(Qp + 4);
  const float* Kb = K + (size_t)b * LSEQ * D_MODEL + col;
  const int* sp = sidx + (size_t)q * S;

  auto rowp = [&](int j) -> const float* {
    int jj = j + s;
    int row = sp[(jj < S) ? jj : (S - 1)];
    return Kb + (size_t)row * D_MODEL;
  };

  const float* pr0 = rowp(0);
  float4 a0 = *(const float4*)pr0, b0 = *(const float4*)(pr0 + 4);
  const float* pr1 = rowp(2);
  float4 a1 = *(const float4*)pr1, b1 = *(const float4*)(pr1 + 4);

  float mx = -3.4e38f, sum = 0.0f;
  for (int j = 0; j < S; j += 2) {
    const float4 ca = a0, cb = b0;
    a0 = a1; b0 = b1;
    const float* pn = rowp(j + 4);
    a1 = *(const float4*)pn;
    b1 = *(const float4*)(pn + 4);
    float p = ca.x * q0.x + ca.y * q0.y + ca.z * q0.z + ca.w * q0.w +
              cb.x * q1.x + cb.y * q1.y + cb.z * q1.z + cb.w * q1.w;
    p += __shfl_xor(p, 1, 64);
    p += __shfl_xor(p, 2, 64);
    p += __shfl_xor(p, 4, 64);   // 8-lane group done
    if (j + s < S) {
      mx = fmaxf(mx, p);
      sum += p;
    }
  }
  mx = fmaxf(mx, __shfl_xor(mx, 32, 64));
  sum += __shfl_xor(sum, 32, 64);
  if (s == 0 && d == 0)
    M[((size_t)(b * NHEADS + h)) * LSEQ + q] = mx - sum / (float)S;
}

// ===================== top-U indices per (b,h) =============================
__global__ __launch_bounds__(256) void topk_kernel(
    const float* __restrict__ M, int* __restrict__ Mtop, int U) {
  __shared__ float vals[LSEQ];
  __shared__ float rmax[256];
  __shared__ int ridx[256];
  int bh = blockIdx.x;
  int t = threadIdx.x;
  for (int i = t; i < LSEQ; i += 256) vals[i] = M[(size_t)bh * LSEQ + i];
  __syncthreads();
  for (int it = 0; it < U; ++it) {
    float best = -3.4e38f; int bi = -1;
    for (int i = t; i < LSEQ; i += 256) {
      float v = vals[i];
      if (v > best) { best = v; bi = i; }
    }
    rmax[t] = best; ridx[t] = bi;
    __syncthreads();
    for (int s = 128; s > 0; s >>= 1) {
      if (t < s) {
        if (rmax[t + s] > rmax[t]) { rmax[t] = rmax[t + s]; ridx[t] = ridx[t + s]; }
      }
      __syncthreads();
    }
    if (t == 0) {
      Mtop[(size_t)bh * U + it] = ridx[0];
      vals[ridx[0]] = -3.4e38f;
    }
    __syncthreads();
  }
}

// ============== flash attention over top-U rows, key-split =================
// MFMA QK^T (swapped: S^T = mfma(K, Q)) + fp32 VALU PV.
__global__ __launch_bounds__(256, 2) void attn_flash(
    const float* __restrict__ Q, const float* __restrict__ K,
    const float* __restrict__ V, const int* __restrict__ Mtop,
    float* __restrict__ part_ctx, float* __restrict__ part_m,
    float* __restrict__ part_l, int U, int nsplit, int chunks_per_block) {
  __shared__ u16 KhS[64 * 72];
  __shared__ u16 KlS[64 * 72];
  __shared__ float VsS[64 * 68];
  const int bh = blockIdx.y, split = blockIdx.x;
  const int h = bh & (NHEADS - 1), b = bh >> 3;
  const int t = threadIdx.x, w = t >> 6, lane = t & 63;
  const int fr = lane & 15, quad = lane >> 4;

  const int qi = w * 16 + fr;
  const int qrow = (qi < U) ? Mtop[(size_t)bh * U + qi] : Mtop[(size_t)bh * U];
  const float4* Qr = (const float4*)(Q + ((size_t)(b * LSEQ) + qrow) * D_MODEL + h * EDIM);
  float4 qa = Qr[quad * 2], qb = Qr[quad * 2 + 1];
  float4 qc = Qr[quad * 2 + 8], qd = Qr[quad * 2 + 9];
  short8 qh0, ql0, qh1, ql1;
  {
    u16 hh, ll;
    split2(qa.x, hh, ll); qh0[0] = (short)hh; ql0[0] = (short)ll;
    split2(qa.y, hh, ll); qh0[1] = (short)hh; ql0[1] = (short)ll;
    split2(qa.z, hh, ll); qh0[2] = (short)hh; ql0[2] = (short)ll;
    split2(qa.w, hh, ll); qh0[3] = (short)hh; ql0[3] = (short)ll;
    split2(qb.x, hh, ll); qh0[4] = (short)hh; ql0[4] = (short)ll;
    split2(qb.y, hh, ll); qh0[5] = (short)hh; ql0[5] = (short)ll;
    split2(qb.z, hh, ll); qh0[6] = (short)hh; ql0[6] = (short)ll;
    split2(qb.w, hh, ll); qh0[7] = (short)hh; ql0[7] = (short)ll;
    split2(qc.x, hh, ll); qh1[0] = (short)hh; ql1[0] = (short)ll;
    split2(qc.y, hh, ll); qh1[1] = (short)hh; ql1[1] = (short)ll;
    split2(qc.z, hh, ll); qh1[2] = (short)hh; ql1[2] = (short)ll;
    split2(qc.w, hh, ll); qh1[3] = (short)hh; ql1[3] = (short)ll;
    split2(qd.x, hh, ll); qh1[4] = (short)hh; ql1[4] = (short)ll;
    split2(qd.y, hh, ll); qh1[5] = (short)hh; ql1[5] = (short)ll;
    split2(qd.z, hh, ll); qh1[6] = (short)hh; ql1[6] = (short)ll;
    split2(qd.w, hh, ll); qh1[7] = (short)hh; ql1[7] = (short)ll;
  }

  float4 c4[16];
#pragma unroll
  for (int i = 0; i < 16; ++i) c4[i] = make_float4(0.f, 0.f, 0.f, 0.f);
  float m = -1e30f, l = 0.0f;

  const int r = t >> 2, cg = t & 3;

  const int k_base = split * (chunks_per_block * 64);
  for (int c = 0; c < chunks_per_block; ++c) {
    const int k0 = k_base + c * 64;
    const float4* Kg4 = (const float4*)(K + ((size_t)(b * LSEQ) + k0 + r) * D_MODEL + h * EDIM);
    const float4* Vg4 = (const float4*)(V + ((size_t)(b * LSEQ) + k0 + r) * D_MODEL + h * EDIM);
#pragma unroll
    for (int i = 0; i < 4; ++i) {
      const int f4 = cg + 4 * i;
      float4 kv = Kg4[f4];
      float4 vv = Vg4[f4];
      ushort4 hh, ll;
      split2(kv.x, hh.x, ll.x);
      split2(kv.y, hh.y, ll.y);
      split2(kv.z, hh.z, ll.z);
      split2(kv.w, hh.w, ll.w);
      *(ushort4*)&KhS[r * 72 + f4 * 4] = hh;
      *(ushort4*)&KlS[r * 72 + f4 * 4] = ll;
      *(float4*)&VsS[r * 68 + f4 * 4] = vv;
    }
    __syncthreads();

    f32x4 acc[4];
#pragma unroll
    for (int mt = 0; mt < 4; ++mt) acc[mt] = (f32x4){0.f, 0.f, 0.f, 0.f};
#pragma unroll
    for (int mt = 0; mt < 4; ++mt) {
      short8 kh = *(const short8*)&KhS[(mt * 16 + fr) * 72 + quad * 8];
      short8 kl = *(const short8*)&KlS[(mt * 16 + fr) * 72 + quad * 8];
      acc[mt] = __builtin_amdgcn_mfma_f32_16x16x32_bf16(kh, qh0, acc[mt], 0, 0, 0);
      acc[mt] = __builtin_amdgcn_mfma_f32_16x16x32_bf16(kh, ql0, acc[mt], 0, 0, 0);
      acc[mt] = __builtin_amdgcn_mfma_f32_16x16x32_bf16(kl, qh0, acc[mt], 0, 0, 0);
    }
#pragma unroll
    for (int mt = 0; mt < 4; ++mt) {
      short8 kh = *(const short8*)&KhS[(mt * 16 + fr) * 72 + 32 + quad * 8];
      short8 kl = *(const short8*)&KlS[(mt * 16 + fr) * 72 + 32 + quad * 8];
      acc[mt] = __builtin_amdgcn_mfma_f32_16x16x32_bf16(kh, qh1, acc[mt], 0, 0, 0);
      acc[mt] = __builtin_amdgcn_mfma_f32_16x16x32_bf16(kh, ql1, acc[mt], 0, 0, 0);
      acc[mt] = __builtin_amdgcn_mfma_f32_16x16x32_bf16(kl, qh1, acc[mt], 0, 0, 0);
    }

    float cm = -3.4e38f;
#pragma unroll
    for (int mt = 0; mt < 4; ++mt) {
#pragma unroll
      for (int rr = 0; rr < 4; ++rr) {
        float s = acc[mt][rr] * 0.125f;
        acc[mt][rr] = s;
        cm = fmaxf(cm, s);
      }
    }
    cm = fmaxf(cm, __shfl_xor(cm, 16, 64));
    cm = fmaxf(cm, __shfl_xor(cm, 32, 64));
    float mn = fmaxf(m, cm);
    if (mn > m) {
      float f = __expf(m - mn);
      l *= f;
#pragma unroll
      for (int i = 0; i < 16; ++i) {
        c4[i].x *= f; c4[i].y *= f; c4[i].z *= f; c4[i].w *= f;
      }
      m = mn;
    }
    float psum = 0.0f;
#pragma unroll
    for (int mt = 0; mt < 4; ++mt) {
#pragma unroll
      for (int rr = 0; rr < 4; ++rr) {
        float p = __expf(acc[mt][rr] - m);
        acc[mt][rr] = p;
        psum += p;
      }
    }
    l += psum;

#pragma unroll
    for (int mt = 0; mt < 4; ++mt) {
#pragma unroll
      for (int rr = 0; rr < 4; ++rr) {
        const int krow = mt * 16 + quad * 4 + rr;
        const float4* vr = (const float4*)&VsS[krow * 68];
        const float p = acc[mt][rr];
#pragma unroll
        for (int i = 0; i < 16; ++i) {
          float4 vv = vr[i];
          c4[i].x += p * vv.x; c4[i].y += p * vv.y;
          c4[i].z += p * vv.z; c4[i].w += p * vv.w;
        }
      }
    }
    __syncthreads();
  }

#pragma unroll
  for (int i = 0; i < 16; ++i) {
    c4[i].x += __shfl_xor(c4[i].x, 16, 64);
    c4[i].y += __shfl_xor(c4[i].y, 16, 64);
    c4[i].z += __shfl_xor(c4[i].z, 16, 64);
    c4[i].w += __shfl_xor(c4[i].w, 16, 64);
    c4[i].x += __shfl_xor(c4[i].x, 32, 64);
    c4[i].y += __shfl_xor(c4[i].y, 32, 64);
    c4[i].z += __shfl_xor(c4[i].z, 32, 64);
    c4[i].w += __shfl_xor(c4[i].w, 32, 64);
  }
  l += __shfl_xor(l, 16, 64);
  l += __shfl_xor(l, 32, 64);

  if (quad == 0 && qi < U) {
    part_m[(size_t)(bh * nsplit + split) * 64 + qi] = m;
    part_l[(size_t)(bh * nsplit + split) * 64 + qi] = l;
  }
  float* pc = part_ctx + (size_t)(bh * nsplit + split) * 4096;
  if (quad == 0) {
#pragma unroll
    for (int ii = 0; ii < 16; ++ii) pc[ii * 64 + qi] = (&c4[ii >> 2].x)[ii & 3];
  } else if (quad == 1) {
#pragma unroll
    for (int ii = 0; ii < 16; ++ii) pc[(16 + ii) * 64 + qi] = (&c4[4 + (ii >> 2)].x)[ii & 3];
  } else if (quad == 2) {
#pragma unroll
    for (int ii = 0; ii < 16; ++ii) pc[(32 + ii) * 64 + qi] = (&c4[8 + (ii >> 2)].x)[ii & 3];
  } else {
#pragma unroll
    for (int ii = 0; ii < 16; ++ii) pc[(48 + ii) * 64 + qi] = (&c4[12 + (ii >> 2)].x)[ii & 3];
  }
}

// =================== combine key-split flash partials ======================
__global__ __launch_bounds__(256) void attn_combine(
    const float* __restrict__ part_ctx, const float* __restrict__ part_m,
    const float* __restrict__ part_l, float* __restrict__ ctxTop,
    int U, int nsplit) {
  __shared__ float F[16][64];
  const int bh = blockIdx.x;
  const int t = threadIdx.x, lane = t & 63, grp = t >> 6;
  if (grp == 0) {
    float M = -3.4e38f;
    for (int s = 0; s < nsplit; ++s)
      M = fmaxf(M, part_m[(size_t)(bh * nsplit + s) * 64 + lane]);
    float L = 0.0f;
    for (int s = 0; s < nsplit; ++s)
      L += part_l[(size_t)(bh * nsplit + s) * 64 + lane] *
           __expf(part_m[(size_t)(bh * nsplit + s) * 64 + lane] - M);
    float invL = 1.0f / L;
    for (int s = 0; s < nsplit; ++s)
      F[s][lane] = __expf(part_m[(size_t)(bh * nsplit + s) * 64 + lane] - M) * invL;
  }
  __syncthreads();
  for (int ei = 0; ei < 16; ++ei) {
    int e = grp * 16 + ei;
    float acc = 0.0f;
    for (int s = 0; s < nsplit; ++s)
      acc += F[s][lane] * part_ctx[(size_t)(bh * nsplit + s) * 4096 + e * 64 + lane];
    if (lane < U) ctxTop[((size_t)bh * U + lane) * 64 + e] = acc;
  }
}

// ====================== V.mean over keys per (b,h) =========================
__global__ __launch_bounds__(256) void vmean_kernel(
    const float* __restrict__ V, float* __restrict__ Vm) {
  __shared__ float part[4][EDIM];
  int bh = blockIdx.x;
  int h = bh & (NHEADS - 1), b = bh >> 3;
  int t = threadIdx.x;
  int e = t & 63, c = t >> 6;
  float s = 0.0f;
  for (int k = c * (LSEQ / 4); k < (c + 1) * (LSEQ / 4); ++k)
    s += V[((size_t)b * LSEQ + k) * D_MODEL + h * EDIM + e];
  part[c][e] = s;
  __syncthreads();
  if (c == 0)
    Vm[(size_t)bh * EDIM + e] =
        (part[0][e] + part[1][e] + part[2][e] + part[3][e]) * (1.0f / (float)LSEQ);
}

// ============ base_out[b] = concat_h(Vmean[b,h]) @ W_out + b_out ===========
__global__ __launch_bounds__(256) void base_out_kernel(
    const float* __restrict__ Vm, const float* __restrict__ Wout,
    const float* __restrict__ bout, float* __restrict__ base) {
  __shared__ float cb[D_MODEL];
  int b = blockIdx.x;
  int t = threadIdx.x;
  for (int d = t; d < D_MODEL; d += 256) cb[d] = Vm[(size_t)b * D_MODEL + d];
  __syncthreads();
  for (int n = t; n < D_MODEL; n += 256) {
    float s = bout[n];
    for (int d = 0; d < D_MODEL; ++d) s += cb[d] * Wout[(size_t)d * D_MODEL + n];
    base[(size_t)b * D_MODEL + n] = s;
  }
}

// ================== broadcast base row into all output rows ================
__global__ __launch_bounds__(256) void fill_out(
    const float* __restrict__ base, float* __restrict__ out) {
  size_t i = (size_t)blockIdx.x * 256 + threadIdx.x;
  int n4 = (int)(i & 127);
  size_t bq = i >> 7;
  int b = (int)(bq >> 12);
  float4 v = ((const float4*)base)[(size_t)b * 128 + n4];
  ((float4*)out)[i] = v;
}

// ====== add (ctxTop - Vmean) @ W_out[h-slice] into the top rows (MFMA) =====
// One block per (b,h): [64u x 64e] @ [64e x 512n] via 16x16x32 split-bf16.
// dlt staged in LDS [64][72] (pad: unpadded 64-col rows are a 16-way bank
// conflict since bank = f(col) only). B-fragments read from the transposed
// W_out planes (WoutT[n][e], L2-resident). Atomic scatter into out rows
// (cross-head same-row collisions require add).
__global__ __launch_bounds__(256, 1) void delta_out_mfma(
    const float* __restrict__ ctxTop, const float* __restrict__ Vm,
    const int* __restrict__ Mtop, const u16* __restrict__ WoutTP,
    float* __restrict__ out, int U) {
  __shared__ u16 Dh[64 * 72];
  __shared__ u16 Dl[64 * 72];
  __shared__ int qr[64];
  const int bh = blockIdx.x;
  const int h = bh & (NHEADS - 1), b = bh >> 3;
  const int t = threadIdx.x, lane = t & 63, wv = t >> 6;
  const int fr = lane & 15, quad = lane >> 4;

  // stage dlt rows: thread covers row r = t>>2, cols (t&3)*16 .. +16
  {
    const int r = t >> 2, c0 = (t & 3) * 16;
#pragma unroll
    for (int j = 0; j < 4; ++j) {
      float4 v = make_float4(0.f, 0.f, 0.f, 0.f);
      if (r < U) {
        float4 cv = *(const float4*)(ctxTop + ((size_t)bh * U + r) * EDIM + c0 + j * 4);
        float4 mv = *(const float4*)(Vm + (size_t)bh * EDIM + c0 + j * 4);
        v = make_float4(cv.x - mv.x, cv.y - mv.y, cv.z - mv.z, cv.w - mv.w);
      }
      ushort4 hh, ll;
      split2(v.x, hh.x, ll.x);
      split2(v.y, hh.y, ll.y);
      split2(v.z, hh.z, ll.z);
      split2(v.w, hh.w, ll.w);
      *(ushort4*)&Dh[r * 72 + c0 + j * 4] = hh;
      *(ushort4*)&Dl[r * 72 + c0 + j * 4] = ll;
    }
  }
  if (t < 64) qr[t] = (t < U) ? Mtop[(size_t)bh * U + t] : -1;
  __syncthreads();

  // GEMM: wave wv owns n-chunk [wv*128, wv*128+128)
  f32x4 acc[32];   // [mt(4)][nt(8)]
#pragma unroll
  for (int i = 0; i < 32; ++i) acc[i] = (f32x4){0.f, 0.f, 0.f, 0.f};

  const u16* Wh = WoutTP;            // [512n][512e] plane h
  const u16* Wl = WoutTP + 262144;   // plane l

#pragma unroll
  for (int ks = 0; ks < 2; ++ks) {
    short8 a_h[4], a_l[4];
#pragma unroll
    for (int mt = 0; mt < 4; ++mt) {
      a_h[mt] = *(const short8*)&Dh[(mt * 16 + fr) * 72 + ks * 32 + quad * 8];
      a_l[mt] = *(const short8*)&Dl[(mt * 16 + fr) * 72 + ks * 32 + quad * 8];
    }
#pragma unroll
    for (int nt = 0; nt < 8; ++nt) {
      const int n = wv * 128 + nt * 16 + fr;
      const size_t off = (size_t)n * 512 + h * EDIM + ks * 32 + quad * 8;
      short8 b_h = *(const short8*)&Wh[off];
      short8 b_l = *(const short8*)&Wl[off];
#pragma unroll
      for (int mt = 0; mt < 4; ++mt) {
        acc[mt * 8 + nt] = __builtin_amdgcn_mfma_f32_16x16x32_bf16(
            a_h[mt], b_h, acc[mt * 8 + nt], 0, 0, 0);
        acc[mt * 8 + nt] = __builtin_amdgcn_mfma_f32_16x16x32_bf16(
            a_h[mt], b_l, acc[mt * 8 + nt], 0, 0, 0);
        acc[mt * 8 + nt] = __builtin_amdgcn_mfma_f32_16x16x32_bf16(
            a_l[mt], b_h, acc[mt * 8 + nt], 0, 0, 0);
      }
    }
  }

  // scatter: D row = mt*16 + quad*4 + r4 (u index), col = wv*128 + nt*16 + fr
  int qreg[16];
#pragma unroll
  for (int mt = 0; mt < 4; ++mt)
#pragma unroll
    for (int r4 = 0; r4 < 4; ++r4) qreg[mt * 4 + r4] = qr[mt * 16 + quad * 4 + r4];
#pragma unroll
  for (int mt = 0; mt < 4; ++mt)
#pragma unroll
    for (int nt = 0; nt < 8; ++nt) {
      const f32x4 a = acc[mt * 8 + nt];
      const int n = wv * 128 + nt * 16 + fr;
#pragma unroll
      for (int r4 = 0; r4 < 4; ++r4) {
        const int q = qreg[mt * 4 + r4];
        if (q >= 0)
          atomicAdd(out + ((size_t)b * LSEQ + q) * D_MODEL + n, a[r4]);
      }
    }
}

// ===========================================================================
extern "C" void kernel_launch(void* const* d_in, const int* in_sizes, int n_in,
                              void* d_out, int out_size, void* d_ws, size_t ws_size,
                              hipStream_t stream) {
  const float* query  = (const float*)d_in[0];
  const float* key_in = (const float*)d_in[1];
  const float* value  = (const float*)d_in[2];
  const float* W_Q    = (const float*)d_in[3];
  const float* W_K    = (const float*)d_in[4];
  const float* W_V    = (const float*)d_in[5];
  const float* W_out  = (const float*)d_in[6];
  const float* b_out  = (const float*)d_in[7];
  const int*   sidx   = (const int*)d_in[8];
  float* out = (float*)d_out;

  const int S = in_sizes[8] / LSEQ;   // 41
  const int U = S;

  char* ws = (char*)d_ws;
  size_t o = 0;
  float* Qf     = (float*)(ws + o); o += (size_t)BATCH * LSEQ * D_MODEL * 4;
  float* Kf     = (float*)(ws + o); o += (size_t)BATCH * LSEQ * D_MODEL * 4;
  float* Vf     = (float*)(ws + o); o += (size_t)BATCH * LSEQ * D_MODEL * 4;
  int*   Mtop   = (int*)  (ws + o); o += ((size_t)64 * U * 4 + 255) & ~255ULL;
  float* ctxTop = (float*)(ws + o); o += ((size_t)64 * U * EDIM * 4 + 255) & ~255ULL;
  float* Vm     = (float*)(ws + o); o += 16384;
  float* baseO  = (float*)(ws + o); o += 16384;
  u16*   Wpl    = (u16*)  (ws + o); o += (size_t)4 * 524288 * 2;   // 4 MB
  size_t unionOff = o;   // X planes / M / flash partials (disjoint lifetimes)

  // adaptive M-chunking so the 2 split planes fit
  int nchunk = 1;
  while (nchunk < 16 &&
         unionOff + 2 * ((size_t)(32768 / nchunk) * 512 * 2) > ws_size)
    nchunk <<= 1;
  const int Mchunk = 32768 / nchunk;
  u16* planes = (u16*)(ws + unionOff);
  const int planeStride = Mchunk * 512;

  float* M = (float*)(ws + unionOff);            // 1 MB, after gemms
  int nsplit = 16;
  for (;;) {
    size_t need = unionOff + 2 * ((size_t)64 * nsplit * 64 * 4)
                  + (size_t)64 * nsplit * 4096 * 4;
    if (need <= ws_size || nsplit == 1) break;
    nsplit >>= 1;
  }
  float* part_m   = (float*)(ws + unionOff);
  float* part_l   = part_m + (size_t)64 * nsplit * 64;
  float* part_ctx = part_l + (size_t)64 * nsplit * 64;
  const int chunks_per_block = 64 / nsplit;

  // ---- projections via split-bf16 MFMA (fused 3-term, single K-sweep) ----
  cvt_w<<<dim3(8, 8, 4), 256, 0, stream>>>(W_Q, W_K, W_V, W_out, Wpl);
  const float* Xsrc[3] = {query, key_in, value};
  float* Ydst[3] = {Qf, Kf, Vf};
  for (int g = 0; g < 3; ++g) {
    for (int c = 0; c < nchunk; ++c) {
      const float* xc = Xsrc[g] + (size_t)c * Mchunk * 512;
      float* yc = Ydst[g] + (size_t)c * Mchunk * 512;
      cvt_x<<<(Mchunk * 512) / 1024, 256, 0, stream>>>(xc, planes, planeStride);
      gemm_mfma<<<dim3(Mchunk / 128, 4), 256, 0, stream>>>(
          planes, planeStride, Wpl + (size_t)g * 524288, yc);
    }
  }

  qk_sample_half<<<(BATCH * LSEQ) / 4, 256, 0, stream>>>(Qf, Kf, sidx, M, S, 0);
  qk_sample_half<<<(BATCH * LSEQ) / 4, 256, 0, stream>>>(Qf, Kf, sidx, M, S, 1);
  topk_kernel<<<BATCH * NHEADS, 256, 0, stream>>>(M, Mtop, U);
  attn_flash<<<dim3(nsplit, BATCH * NHEADS), 256, 0, stream>>>(
      Qf, Kf, Vf, Mtop, part_ctx, part_m, part_l, U, nsplit, chunks_per_block);
  attn_combine<<<BATCH * NHEADS, 256, 0, stream>>>(
      part_ctx, part_m, part_l, ctxTop, U, nsplit);
  vmean_kernel<<<BATCH * NHEADS, 256, 0, stream>>>(Vf, Vm);
  base_out_kernel<<<BATCH, 256, 0, stream>>>(Vm, W_out, b_out, baseO);
  fill_out<<<(BATCH * LSEQ * (D_MODEL / 4)) / 256, 256, 0, stream>>>(baseO, out);
  delta_out_mfma<<<BATCH * NHEADS, 256, 0, stream>>>(
      ctxTop, Vm, Mtop, Wpl + (size_t)3 * 524288, out, U);
}

// Round 5
// 779.233 us; speedup vs baseline: 1.5140x; 1.0818x over previous
//
#include <hip/hip_runtime.h>
#include <cstdint>
#include <cstddef>

#define D_MODEL 512
#define NHEADS  8
#define EDIM    64
#define BATCH   8
#define LSEQ    4096

typedef unsigned short u16;
typedef __attribute__((ext_vector_type(8))) short short8;
typedef __attribute__((ext_vector_type(4))) float f32x4;

// ===================== fp32 -> 2-term bf16 split ===========================
__device__ __forceinline__ u16 bf16_rne(float x) {
  unsigned int u = __float_as_uint(x);
  u += 0x7FFFu + ((u >> 16) & 1u);
  return (u16)(u >> 16);
}
__device__ __forceinline__ void split2(float x, u16& h, u16& l) {
  h = bf16_rne(x);
  float hf = __uint_as_float((unsigned int)h << 16);
  l = bf16_rne(x - hf);
}

// W (512x512 fp32, k-major) -> transposed planes WT[n][k] (h,l), 4 weights
// (W_Q, W_K, W_V for the projections; W_out for the MFMA delta epilogue)
__global__ __launch_bounds__(256) void cvt_w(
    const float* __restrict__ W0, const float* __restrict__ W1,
    const float* __restrict__ W2, const float* __restrict__ W3,
    u16* __restrict__ out) {
  const float* W = (blockIdx.z == 0) ? W0 : ((blockIdx.z == 1) ? W1 :
                   ((blockIdx.z == 2) ? W2 : W3));
  u16* P = out + (size_t)blockIdx.z * 524288;       // 2 planes of 262144
  __shared__ float tile[64][65];
  const int k0 = blockIdx.x * 64, n0 = blockIdx.y * 64;
  const int t = threadIdx.x;
  const int tr = t >> 4, tc = (t & 15) * 4;
#pragma unroll
  for (int j = 0; j < 4; ++j) {
    int kr = tr + j * 16;
    float4 v = *(const float4*)(W + (size_t)(k0 + kr) * 512 + n0 + tc);
    tile[kr][tc + 0] = v.x; tile[kr][tc + 1] = v.y;
    tile[kr][tc + 2] = v.z; tile[kr][tc + 3] = v.w;
  }
  __syncthreads();
#pragma unroll
  for (int j = 0; j < 4; ++j) {
    int nr = tr + j * 16;
    ushort4 h, l;
    split2(tile[tc + 0][nr], h.x, l.x);
    split2(tile[tc + 1][nr], h.y, l.y);
    split2(tile[tc + 2][nr], h.z, l.z);
    split2(tile[tc + 3][nr], h.w, l.w);
    size_t off = (size_t)(n0 + nr) * 512 + k0 + tc;
    *(ushort4*)(P + off) = h;
    *(ushort4*)(P + 262144 + off) = l;
  }
}

__device__ __forceinline__ void gld_lds16(const char* g, char* l) {
  __builtin_amdgcn_global_load_lds((const __attribute__((address_space(1))) void*)g,
                                   (__attribute__((address_space(3))) void*)l, 16, 0, 0);
}

// ========== fused fp32->split-bf16 + MFMA GEMM: Y = X @ W ==================
// 128x128 tile, BK=32, 4 waves. A staged from fp32 X with in-register h/l
// split, written to padded [128][40] LDS rows (stride-40 breaks the
// even/odd-row bank aliasing of stride-32). B from pre-converted planes via
// global_load_lds. Fused 3-term: acc += Ah*Bh + Ah*Bl + Al*Bh (~2^-18 rel).
// Grid (4 bn, 256 bm): same-bm blocks dispatch-adjacent -> A re-reads L3-hot.
__global__ __launch_bounds__(256, 2) void gemm_fused(
    const float* __restrict__ X, const u16* __restrict__ WP,
    float* __restrict__ Y) {
  __shared__ u16 Ah[128 * 40];
  __shared__ u16 Al[128 * 40];
  __shared__ u16 Bh[128 * 32];
  __shared__ u16 Bl[128 * 32];
  const int tid = threadIdx.x;
  const int lane = tid & 63, wv = tid >> 6;
  const int wm = (wv & 1) * 64, wn = (wv >> 1) * 64;
  const int bn = blockIdx.x * 128, bm = blockIdx.y * 128;
  const int fr = lane & 15, quad = lane >> 4;
  const int sRow = tid >> 2, sColB = (tid & 3) * 16;
  const int ar = tid >> 1, ac = (tid & 1) * 16;   // A staging: row, col half

  f32x4 acc[16];
#pragma unroll
  for (int i = 0; i < 16; ++i) acc[i] = (f32x4){0.f, 0.f, 0.f, 0.f};

  const u16* Wh = WP;
  const u16* Wl = WP + 262144;
  const float* Arow = X + (size_t)(bm + ar) * 512 + ac;

  union V8 { ushort4 v4[2]; short8 v8; };

  for (int kk = 0; kk < 16; ++kk) {
    // ---- A: fp32 load -> split -> LDS (padded rows) ----
    float4 x0 = *(const float4*)(Arow + kk * 32);
    float4 x1 = *(const float4*)(Arow + kk * 32 + 4);
    float4 x2 = *(const float4*)(Arow + kk * 32 + 8);
    float4 x3 = *(const float4*)(Arow + kk * 32 + 12);
    // ---- B: global_load_lds from planes ----
#pragma unroll
    for (int j = 0; j < 2; ++j) {
      const size_t rB = (size_t)(bn + j * 64 + sRow) * 512 + kk * 32;
      const int lo = (j * 256 + wv * 64) * 16;
      gld_lds16((const char*)(Wh + rB) + sColB, (char*)Bh + lo);
      gld_lds16((const char*)(Wl + rB) + sColB, (char*)Bl + lo);
    }
    V8 h0, l0, h1, l1;
    split2(x0.x, h0.v4[0].x, l0.v4[0].x);
    split2(x0.y, h0.v4[0].y, l0.v4[0].y);
    split2(x0.z, h0.v4[0].z, l0.v4[0].z);
    split2(x0.w, h0.v4[0].w, l0.v4[0].w);
    split2(x1.x, h0.v4[1].x, l0.v4[1].x);
    split2(x1.y, h0.v4[1].y, l0.v4[1].y);
    split2(x1.z, h0.v4[1].z, l0.v4[1].z);
    split2(x1.w, h0.v4[1].w, l0.v4[1].w);
    split2(x2.x, h1.v4[0].x, l1.v4[0].x);
    split2(x2.y, h1.v4[0].y, l1.v4[0].y);
    split2(x2.z, h1.v4[0].z, l1.v4[0].z);
    split2(x2.w, h1.v4[0].w, l1.v4[0].w);
    split2(x3.x, h1.v4[1].x, l1.v4[1].x);
    split2(x3.y, h1.v4[1].y, l1.v4[1].y);
    split2(x3.z, h1.v4[1].z, l1.v4[1].z);
    split2(x3.w, h1.v4[1].w, l1.v4[1].w);
    *(short8*)&Ah[ar * 40 + ac]     = h0.v8;
    *(short8*)&Ah[ar * 40 + ac + 8] = h1.v8;
    *(short8*)&Al[ar * 40 + ac]     = l0.v8;
    *(short8*)&Al[ar * 40 + ac + 8] = l1.v8;
    __syncthreads();
    short8 ah[4], al[4], bh[4], bl[4];
#pragma unroll
    for (int mi = 0; mi < 4; ++mi) {
      ah[mi] = *(const short8*)&Ah[(wm + mi * 16 + fr) * 40 + quad * 8];
      al[mi] = *(const short8*)&Al[(wm + mi * 16 + fr) * 40 + quad * 8];
    }
#pragma unroll
    for (int ni = 0; ni < 4; ++ni) {
      bh[ni] = *(const short8*)&Bh[(wn + ni * 16 + fr) * 32 + quad * 8];
      bl[ni] = *(const short8*)&Bl[(wn + ni * 16 + fr) * 32 + quad * 8];
    }
#pragma unroll
    for (int mi = 0; mi < 4; ++mi)
#pragma unroll
      for (int ni = 0; ni < 4; ++ni)
        acc[mi * 4 + ni] = __builtin_amdgcn_mfma_f32_16x16x32_bf16(
            ah[mi], bh[ni], acc[mi * 4 + ni], 0, 0, 0);
#pragma unroll
    for (int mi = 0; mi < 4; ++mi)
#pragma unroll
      for (int ni = 0; ni < 4; ++ni)
        acc[mi * 4 + ni] = __builtin_amdgcn_mfma_f32_16x16x32_bf16(
            ah[mi], bl[ni], acc[mi * 4 + ni], 0, 0, 0);
#pragma unroll
    for (int mi = 0; mi < 4; ++mi)
#pragma unroll
      for (int ni = 0; ni < 4; ++ni)
        acc[mi * 4 + ni] = __builtin_amdgcn_mfma_f32_16x16x32_bf16(
            al[mi], bh[ni], acc[mi * 4 + ni], 0, 0, 0);
    __syncthreads();
  }
#pragma unroll
  for (int mi = 0; mi < 4; ++mi)
#pragma unroll
    for (int ni = 0; ni < 4; ++ni) {
      const f32x4 a = acc[mi * 4 + ni];
      float* yp = Y + (size_t)(bm + wm + mi * 16 + quad * 4) * 512 + (bn + wn + ni * 16 + fr);
#pragma unroll
      for (int r = 0; r < 4; ++r) yp[(size_t)r * 512] = a[r];
    }
}

// ================= QK_sample -> M, half-row per pass =======================
// 8-lane dot groups, 2 samples/iter; sample indices prefetched 4 iterations
// ahead, K rows 3 iterations ahead (sp->addr->K chain off the critical path).
__global__ __launch_bounds__(256) void qk_sample_half(
    const float* __restrict__ Q, const float* __restrict__ K,
    const int* __restrict__ sidx, float* __restrict__ M, int S, int hg) {
  const int blk = blockIdx.x;
  const int lane = threadIdx.x & 63;
  const int b = blk & 7;                      // XCD swizzle: batch <-> XCD
  const int q = ((blk >> 3) << 2) + (threadIdx.x >> 6);
  const int s = lane >> 5;                    // sample parity
  const int hl = (lane >> 3) & 3;             // head within group
  const int d = lane & 7;                     // dim octet
  const int h = hg * 4 + hl;
  const int col = hg * 256 + hl * 64 + d * 8;

  const float* Qp = Q + ((size_t)b * LSEQ + q) * D_MODEL + col;
  const float4 q0 = *(const float4*)Qp;
  const float4 q1 = *(const float4*)(Qp + 4);
  const float* Kb = K + (size_t)b * LSEQ * D_MODEL + col;
  const int* sp = sidx + (size_t)q * S;

  auto spclamp = [&](int j) -> int {
    int jj = j + s;
    return sp[(jj < S) ? jj : (S - 1)];
  };

  // index pipeline: 4 iters ahead; K data: 3 iters ahead
  int i0 = spclamp(0), i1 = spclamp(2), i2 = spclamp(4), i3 = spclamp(6);
  const float* p0 = Kb + (size_t)i0 * D_MODEL;
  float4 a0 = *(const float4*)p0, b0 = *(const float4*)(p0 + 4);
  const float* p1 = Kb + (size_t)i1 * D_MODEL;
  float4 a1 = *(const float4*)p1, b1 = *(const float4*)(p1 + 4);
  const float* p2 = Kb + (size_t)i2 * D_MODEL;
  float4 a2 = *(const float4*)p2, b2 = *(const float4*)(p2 + 4);

  float mx = -3.4e38f, sum = 0.0f;
  for (int j = 0; j < S; j += 2) {
    const float4 ca = a0, cb = b0;
    a0 = a1; b0 = b1; a1 = a2; b1 = b2;
    const float* pn = Kb + (size_t)i3 * D_MODEL;
    a2 = *(const float4*)pn;
    b2 = *(const float4*)(pn + 4);
    i3 = spclamp(j + 8);
    float p = ca.x * q0.x + ca.y * q0.y + ca.z * q0.z + ca.w * q0.w +
              cb.x * q1.x + cb.y * q1.y + cb.z * q1.z + cb.w * q1.w;
    p += __shfl_xor(p, 1, 64);
    p += __shfl_xor(p, 2, 64);
    p += __shfl_xor(p, 4, 64);   // 8-lane group done
    if (j + s < S) {
      mx = fmaxf(mx, p);
      sum += p;
    }
  }
  mx = fmaxf(mx, __shfl_xor(mx, 32, 64));
  sum += __shfl_xor(sum, 32, 64);
  if (s == 0 && d == 0)
    M[((size_t)(b * NHEADS + h)) * LSEQ + q] = mx - sum / (float)S;
}

// ===================== top-U indices per (b,h) =============================
__global__ __launch_bounds__(256) void topk_kernel(
    const float* __restrict__ M, int* __restrict__ Mtop, int U) {
  __shared__ float vals[LSEQ];
  __shared__ float rmax[256];
  __shared__ int ridx[256];
  int bh = blockIdx.x;
  int t = threadIdx.x;
  for (int i = t; i < LSEQ; i += 256) vals[i] = M[(size_t)bh * LSEQ + i];
  __syncthreads();
  for (int it = 0; it < U; ++it) {
    float best = -3.4e38f; int bi = -1;
    for (int i = t; i < LSEQ; i += 256) {
      float v = vals[i];
      if (v > best) { best = v; bi = i; }
    }
    rmax[t] = best; ridx[t] = bi;
    __syncthreads();
    for (int s = 128; s > 0; s >>= 1) {
      if (t < s) {
        if (rmax[t + s] > rmax[t]) { rmax[t] = rmax[t + s]; ridx[t] = ridx[t + s]; }
      }
      __syncthreads();
    }
    if (t == 0) {
      Mtop[(size_t)bh * U + it] = ridx[0];
      vals[ridx[0]] = -3.4e38f;
    }
    __syncthreads();
  }
}

// ============== flash attention over top-U rows, key-split =================
// MFMA QK^T (swapped: S^T = mfma(K, Q)) + fp32 VALU PV.
__global__ __launch_bounds__(256, 2) void attn_flash(
    const float* __restrict__ Q, const float* __restrict__ K,
    const float* __restrict__ V, const int* __restrict__ Mtop,
    float* __restrict__ part_ctx, float* __restrict__ part_m,
    float* __restrict__ part_l, int U, int nsplit, int chunks_per_block) {
  __shared__ u16 KhS[64 * 72];
  __shared__ u16 KlS[64 * 72];
  __shared__ float VsS[64 * 68];
  const int bh = blockIdx.y, split = blockIdx.x;
  const int h = bh & (NHEADS - 1), b = bh >> 3;
  const int t = threadIdx.x, w = t >> 6, lane = t & 63;
  const int fr = lane & 15, quad = lane >> 4;

  const int qi = w * 16 + fr;
  const int qrow = (qi < U) ? Mtop[(size_t)bh * U + qi] : Mtop[(size_t)bh * U];
  const float4* Qr = (const float4*)(Q + ((size_t)(b * LSEQ) + qrow) * D_MODEL + h * EDIM);
  float4 qa = Qr[quad * 2], qb = Qr[quad * 2 + 1];
  float4 qc = Qr[quad * 2 + 8], qd = Qr[quad * 2 + 9];
  short8 qh0, ql0, qh1, ql1;
  {
    u16 hh, ll;
    split2(qa.x, hh, ll); qh0[0] = (short)hh; ql0[0] = (short)ll;
    split2(qa.y, hh, ll); qh0[1] = (short)hh; ql0[1] = (short)ll;
    split2(qa.z, hh, ll); qh0[2] = (short)hh; ql0[2] = (short)ll;
    split2(qa.w, hh, ll); qh0[3] = (short)hh; ql0[3] = (short)ll;
    split2(qb.x, hh, ll); qh0[4] = (short)hh; ql0[4] = (short)ll;
    split2(qb.y, hh, ll); qh0[5] = (short)hh; ql0[5] = (short)ll;
    split2(qb.z, hh, ll); qh0[6] = (short)hh; ql0[6] = (short)ll;
    split2(qb.w, hh, ll); qh0[7] = (short)hh; ql0[7] = (short)ll;
    split2(qc.x, hh, ll); qh1[0] = (short)hh; ql1[0] = (short)ll;
    split2(qc.y, hh, ll); qh1[1] = (short)hh; ql1[1] = (short)ll;
    split2(qc.z, hh, ll); qh1[2] = (short)hh; ql1[2] = (short)ll;
    split2(qc.w, hh, ll); qh1[3] = (short)hh; ql1[3] = (short)ll;
    split2(qd.x, hh, ll); qh1[4] = (short)hh; ql1[4] = (short)ll;
    split2(qd.y, hh, ll); qh1[5] = (short)hh; ql1[5] = (short)ll;
    split2(qd.z, hh, ll); qh1[6] = (short)hh; ql1[6] = (short)ll;
    split2(qd.w, hh, ll); qh1[7] = (short)hh; ql1[7] = (short)ll;
  }

  float4 c4[16];
#pragma unroll
  for (int i = 0; i < 16; ++i) c4[i] = make_float4(0.f, 0.f, 0.f, 0.f);
  float m = -1e30f, l = 0.0f;

  const int r = t >> 2, cg = t & 3;

  const int k_base = split * (chunks_per_block * 64);
  for (int c = 0; c < chunks_per_block; ++c) {
    const int k0 = k_base + c * 64;
    const float4* Kg4 = (const float4*)(K + ((size_t)(b * LSEQ) + k0 + r) * D_MODEL + h * EDIM);
    const float4* Vg4 = (const float4*)(V + ((size_t)(b * LSEQ) + k0 + r) * D_MODEL + h * EDIM);
#pragma unroll
    for (int i = 0; i < 4; ++i) {
      const int f4 = cg + 4 * i;
      float4 kv = Kg4[f4];
      float4 vv = Vg4[f4];
      ushort4 hh, ll;
      split2(kv.x, hh.x, ll.x);
      split2(kv.y, hh.y, ll.y);
      split2(kv.z, hh.z, ll.z);
      split2(kv.w, hh.w, ll.w);
      *(ushort4*)&KhS[r * 72 + f4 * 4] = hh;
      *(ushort4*)&KlS[r * 72 + f4 * 4] = ll;
      *(float4*)&VsS[r * 68 + f4 * 4] = vv;
    }
    __syncthreads();

    f32x4 acc[4];
#pragma unroll
    for (int mt = 0; mt < 4; ++mt) acc[mt] = (f32x4){0.f, 0.f, 0.f, 0.f};
#pragma unroll
    for (int mt = 0; mt < 4; ++mt) {
      short8 kh = *(const short8*)&KhS[(mt * 16 + fr) * 72 + quad * 8];
      short8 kl = *(const short8*)&KlS[(mt * 16 + fr) * 72 + quad * 8];
      acc[mt] = __builtin_amdgcn_mfma_f32_16x16x32_bf16(kh, qh0, acc[mt], 0, 0, 0);
      acc[mt] = __builtin_amdgcn_mfma_f32_16x16x32_bf16(kh, ql0, acc[mt], 0, 0, 0);
      acc[mt] = __builtin_amdgcn_mfma_f32_16x16x32_bf16(kl, qh0, acc[mt], 0, 0, 0);
    }
#pragma unroll
    for (int mt = 0; mt < 4; ++mt) {
      short8 kh = *(const short8*)&KhS[(mt * 16 + fr) * 72 + 32 + quad * 8];
      short8 kl = *(const short8*)&KlS[(mt * 16 + fr) * 72 + 32 + quad * 8];
      acc[mt] = __builtin_amdgcn_mfma_f32_16x16x32_bf16(kh, qh1, acc[mt], 0, 0, 0);
      acc[mt] = __builtin_amdgcn_mfma_f32_16x16x32_bf16(kh, ql1, acc[mt], 0, 0, 0);
      acc[mt] = __builtin_amdgcn_mfma_f32_16x16x32_bf16(kl, qh1, acc[mt], 0, 0, 0);
    }

    float cm = -3.4e38f;
#pragma unroll
    for (int mt = 0; mt < 4; ++mt) {
#pragma unroll
      for (int rr = 0; rr < 4; ++rr) {
        float s = acc[mt][rr] * 0.125f;
        acc[mt][rr] = s;
        cm = fmaxf(cm, s);
      }
    }
    cm = fmaxf(cm, __shfl_xor(cm, 16, 64));
    cm = fmaxf(cm, __shfl_xor(cm, 32, 64));
    float mn = fmaxf(m, cm);
    if (mn > m) {
      float f = __expf(m - mn);
      l *= f;
#pragma unroll
      for (int i = 0; i < 16; ++i) {
        c4[i].x *= f; c4[i].y *= f; c4[i].z *= f; c4[i].w *= f;
      }
      m = mn;
    }
    float psum = 0.0f;
#pragma unroll
    for (int mt = 0; mt < 4; ++mt) {
#pragma unroll
      for (int rr = 0; rr < 4; ++rr) {
        float p = __expf(acc[mt][rr] - m);
        acc[mt][rr] = p;
        psum += p;
      }
    }
    l += psum;

#pragma unroll
    for (int mt = 0; mt < 4; ++mt) {
#pragma unroll
      for (int rr = 0; rr < 4; ++rr) {
        const int krow = mt * 16 + quad * 4 + rr;
        const float4* vr = (const float4*)&VsS[krow * 68];
        const float p = acc[mt][rr];
#pragma unroll
        for (int i = 0; i < 16; ++i) {
          float4 vv = vr[i];
          c4[i].x += p * vv.x; c4[i].y += p * vv.y;
          c4[i].z += p * vv.z; c4[i].w += p * vv.w;
        }
      }
    }
    __syncthreads();
  }

#pragma unroll
  for (int i = 0; i < 16; ++i) {
    c4[i].x += __shfl_xor(c4[i].x, 16, 64);
    c4[i].y += __shfl_xor(c4[i].y, 16, 64);
    c4[i].z += __shfl_xor(c4[i].z, 16, 64);
    c4[i].w += __shfl_xor(c4[i].w, 16, 64);
    c4[i].x += __shfl_xor(c4[i].x, 32, 64);
    c4[i].y += __shfl_xor(c4[i].y, 32, 64);
    c4[i].z += __shfl_xor(c4[i].z, 32, 64);
    c4[i].w += __shfl_xor(c4[i].w, 32, 64);
  }
  l += __shfl_xor(l, 16, 64);
  l += __shfl_xor(l, 32, 64);

  if (quad == 0 && qi < U) {
    part_m[(size_t)(bh * nsplit + split) * 64 + qi] = m;
    part_l[(size_t)(bh * nsplit + split) * 64 + qi] = l;
  }
  float* pc = part_ctx + (size_t)(bh * nsplit + split) * 4096;
  if (quad == 0) {
#pragma unroll
    for (int ii = 0; ii < 16; ++ii) pc[ii * 64 + qi] = (&c4[ii >> 2].x)[ii & 3];
  } else if (quad == 1) {
#pragma unroll
    for (int ii = 0; ii < 16; ++ii) pc[(16 + ii) * 64 + qi] = (&c4[4 + (ii >> 2)].x)[ii & 3];
  } else if (quad == 2) {
#pragma unroll
    for (int ii = 0; ii < 16; ++ii) pc[(32 + ii) * 64 + qi] = (&c4[8 + (ii >> 2)].x)[ii & 3];
  } else {
#pragma unroll
    for (int ii = 0; ii < 16; ++ii) pc[(48 + ii) * 64 + qi] = (&c4[12 + (ii >> 2)].x)[ii & 3];
  }
}

// =================== combine key-split flash partials ======================
__global__ __launch_bounds__(256) void attn_combine(
    const float* __restrict__ part_ctx, const float* __restrict__ part_m,
    const float* __restrict__ part_l, float* __restrict__ ctxTop,
    int U, int nsplit) {
  __shared__ float F[16][64];
  const int bh = blockIdx.x;
  const int t = threadIdx.x, lane = t & 63, grp = t >> 6;
  if (grp == 0) {
    float M = -3.4e38f;
    for (int s = 0; s < nsplit; ++s)
      M = fmaxf(M, part_m[(size_t)(bh * nsplit + s) * 64 + lane]);
    float L = 0.0f;
    for (int s = 0; s < nsplit; ++s)
      L += part_l[(size_t)(bh * nsplit + s) * 64 + lane] *
           __expf(part_m[(size_t)(bh * nsplit + s) * 64 + lane] - M);
    float invL = 1.0f / L;
    for (int s = 0; s < nsplit; ++s)
      F[s][lane] = __expf(part_m[(size_t)(bh * nsplit + s) * 64 + lane] - M) * invL;
  }
  __syncthreads();
  for (int ei = 0; ei < 16; ++ei) {
    int e = grp * 16 + ei;
    float acc = 0.0f;
    for (int s = 0; s < nsplit; ++s)
      acc += F[s][lane] * part_ctx[(size_t)(bh * nsplit + s) * 4096 + e * 64 + lane];
    if (lane < U) ctxTop[((size_t)bh * U + lane) * 64 + e] = acc;
  }
}

// ====================== V.mean over keys per (b,h) =========================
__global__ __launch_bounds__(256) void vmean_kernel(
    const float* __restrict__ V, float* __restrict__ Vm) {
  __shared__ float part[4][EDIM];
  int bh = blockIdx.x;
  int h = bh & (NHEADS - 1), b = bh >> 3;
  int t = threadIdx.x;
  int e = t & 63, c = t >> 6;
  float s = 0.0f;
  for (int k = c * (LSEQ / 4); k < (c + 1) * (LSEQ / 4); ++k)
    s += V[((size_t)b * LSEQ + k) * D_MODEL + h * EDIM + e];
  part[c][e] = s;
  __syncthreads();
  if (c == 0)
    Vm[(size_t)bh * EDIM + e] =
        (part[0][e] + part[1][e] + part[2][e] + part[3][e]) * (1.0f / (float)LSEQ);
}

// ============ base_out[b] = concat_h(Vmean[b,h]) @ W_out + b_out ===========
__global__ __launch_bounds__(256) void base_out_kernel(
    const float* __restrict__ Vm, const float* __restrict__ Wout,
    const float* __restrict__ bout, float* __restrict__ base) {
  __shared__ float cb[D_MODEL];
  int b = blockIdx.x;
  int t = threadIdx.x;
  for (int d = t; d < D_MODEL; d += 256) cb[d] = Vm[(size_t)b * D_MODEL + d];
  __syncthreads();
  for (int n = t; n < D_MODEL; n += 256) {
    float s = bout[n];
    for (int d = 0; d < D_MODEL; ++d) s += cb[d] * Wout[(size_t)d * D_MODEL + n];
    base[(size_t)b * D_MODEL + n] = s;
  }
}

// ================== broadcast base row into all output rows ================
__global__ __launch_bounds__(256) void fill_out(
    const float* __restrict__ base, float* __restrict__ out) {
  size_t i = (size_t)blockIdx.x * 256 + threadIdx.x;
  int n4 = (int)(i & 127);
  size_t bq = i >> 7;
  int b = (int)(bq >> 12);
  float4 v = ((const float4*)base)[(size_t)b * 128 + n4];
  ((float4*)out)[i] = v;
}

// ====== add (ctxTop - Vmean) @ W_out[h-slice] into the top rows (MFMA) =====
__global__ __launch_bounds__(256, 1) void delta_out_mfma(
    const float* __restrict__ ctxTop, const float* __restrict__ Vm,
    const int* __restrict__ Mtop, const u16* __restrict__ WoutTP,
    float* __restrict__ out, int U) {
  __shared__ u16 Dh[64 * 72];
  __shared__ u16 Dl[64 * 72];
  __shared__ int qr[64];
  const int bh = blockIdx.x;
  const int h = bh & (NHEADS - 1), b = bh >> 3;
  const int t = threadIdx.x, lane = t & 63, wv = t >> 6;
  const int fr = lane & 15, quad = lane >> 4;

  {
    const int r = t >> 2, c0 = (t & 3) * 16;
#pragma unroll
    for (int j = 0; j < 4; ++j) {
      float4 v = make_float4(0.f, 0.f, 0.f, 0.f);
      if (r < U) {
        float4 cv = *(const float4*)(ctxTop + ((size_t)bh * U + r) * EDIM + c0 + j * 4);
        float4 mv = *(const float4*)(Vm + (size_t)bh * EDIM + c0 + j * 4);
        v = make_float4(cv.x - mv.x, cv.y - mv.y, cv.z - mv.z, cv.w - mv.w);
      }
      ushort4 hh, ll;
      split2(v.x, hh.x, ll.x);
      split2(v.y, hh.y, ll.y);
      split2(v.z, hh.z, ll.z);
      split2(v.w, hh.w, ll.w);
      *(ushort4*)&Dh[r * 72 + c0 + j * 4] = hh;
      *(ushort4*)&Dl[r * 72 + c0 + j * 4] = ll;
    }
  }
  if (t < 64) qr[t] = (t < U) ? Mtop[(size_t)bh * U + t] : -1;
  __syncthreads();

  f32x4 acc[32];   // [mt(4)][nt(8)]
#pragma unroll
  for (int i = 0; i < 32; ++i) acc[i] = (f32x4){0.f, 0.f, 0.f, 0.f};

  const u16* Wh = WoutTP;
  const u16* Wl = WoutTP + 262144;

#pragma unroll
  for (int ks = 0; ks < 2; ++ks) {
    short8 a_h[4], a_l[4];
#pragma unroll
    for (int mt = 0; mt < 4; ++mt) {
      a_h[mt] = *(const short8*)&Dh[(mt * 16 + fr) * 72 + ks * 32 + quad * 8];
      a_l[mt] = *(const short8*)&Dl[(mt * 16 + fr) * 72 + ks * 32 + quad * 8];
    }
#pragma unroll
    for (int nt = 0; nt < 8; ++nt) {
      const int n = wv * 128 + nt * 16 + fr;
      const size_t off = (size_t)n * 512 + h * EDIM + ks * 32 + quad * 8;
      short8 b_h = *(const short8*)&Wh[off];
      short8 b_l = *(const short8*)&Wl[off];
#pragma unroll
      for (int mt = 0; mt < 4; ++mt) {
        acc[mt * 8 + nt] = __builtin_amdgcn_mfma_f32_16x16x32_bf16(
            a_h[mt], b_h, acc[mt * 8 + nt], 0, 0, 0);
        acc[mt * 8 + nt] = __builtin_amdgcn_mfma_f32_16x16x32_bf16(
            a_h[mt], b_l, acc[mt * 8 + nt], 0, 0, 0);
        acc[mt * 8 + nt] = __builtin_amdgcn_mfma_f32_16x16x32_bf16(
            a_l[mt], b_h, acc[mt * 8 + nt], 0, 0, 0);
      }
    }
  }

  int qreg[16];
#pragma unroll
  for (int mt = 0; mt < 4; ++mt)
#pragma unroll
    for (int r4 = 0; r4 < 4; ++r4) qreg[mt * 4 + r4] = qr[mt * 16 + quad * 4 + r4];
#pragma unroll
  for (int mt = 0; mt < 4; ++mt)
#pragma unroll
    for (int nt = 0; nt < 8; ++nt) {
      const f32x4 a = acc[mt * 8 + nt];
      const int n = wv * 128 + nt * 16 + fr;
#pragma unroll
      for (int r4 = 0; r4 < 4; ++r4) {
        const int q = qreg[mt * 4 + r4];
        if (q >= 0)
          atomicAdd(out + ((size_t)b * LSEQ + q) * D_MODEL + n, a[r4]);
      }
    }
}

// ===========================================================================
extern "C" void kernel_launch(void* const* d_in, const int* in_sizes, int n_in,
                              void* d_out, int out_size, void* d_ws, size_t ws_size,
                              hipStream_t stream) {
  const float* query  = (const float*)d_in[0];
  const float* key_in = (const float*)d_in[1];
  const float* value  = (const float*)d_in[2];
  const float* W_Q    = (const float*)d_in[3];
  const float* W_K    = (const float*)d_in[4];
  const float* W_V    = (const float*)d_in[5];
  const float* W_out  = (const float*)d_in[6];
  const float* b_out  = (const float*)d_in[7];
  const int*   sidx   = (const int*)d_in[8];
  float* out = (float*)d_out;

  const int S = in_sizes[8] / LSEQ;   // 41
  const int U = S;

  char* ws = (char*)d_ws;
  size_t o = 0;
  float* Qf     = (float*)(ws + o); o += (size_t)BATCH * LSEQ * D_MODEL * 4;
  float* Kf     = (float*)(ws + o); o += (size_t)BATCH * LSEQ * D_MODEL * 4;
  float* Vf     = (float*)(ws + o); o += (size_t)BATCH * LSEQ * D_MODEL * 4;
  int*   Mtop   = (int*)  (ws + o); o += ((size_t)64 * U * 4 + 255) & ~255ULL;
  float* ctxTop = (float*)(ws + o); o += ((size_t)64 * U * EDIM * 4 + 255) & ~255ULL;
  float* Vm     = (float*)(ws + o); o += 16384;
  float* baseO  = (float*)(ws + o); o += 16384;
  u16*   Wpl    = (u16*)  (ws + o); o += (size_t)4 * 524288 * 2;   // 4 MB
  size_t unionOff = o;   // M / flash partials (disjoint lifetimes)

  float* M = (float*)(ws + unionOff);            // 1 MB
  int nsplit = 16;
  for (;;) {
    size_t need = unionOff + 2 * ((size_t)64 * nsplit * 64 * 4)
                  + (size_t)64 * nsplit * 4096 * 4;
    if (need <= ws_size || nsplit == 1) break;
    nsplit >>= 1;
  }
  float* part_m   = (float*)(ws + unionOff);
  float* part_l   = part_m + (size_t)64 * nsplit * 64;
  float* part_ctx = part_l + (size_t)64 * nsplit * 64;
  const int chunks_per_block = 64 / nsplit;

  // ---- projections via fused fp32->split-bf16 MFMA GEMM ----
  cvt_w<<<dim3(8, 8, 4), 256, 0, stream>>>(W_Q, W_K, W_V, W_out, Wpl);
  gemm_fused<<<dim3(4, 256), 256, 0, stream>>>(query,  Wpl,                       Qf);
  gemm_fused<<<dim3(4, 256), 256, 0, stream>>>(key_in, Wpl + (size_t)1 * 524288,  Kf);
  gemm_fused<<<dim3(4, 256), 256, 0, stream>>>(value,  Wpl + (size_t)2 * 524288,  Vf);

  qk_sample_half<<<(BATCH * LSEQ) / 4, 256, 0, stream>>>(Qf, Kf, sidx, M, S, 0);
  qk_sample_half<<<(BATCH * LSEQ) / 4, 256, 0, stream>>>(Qf, Kf, sidx, M, S, 1);
  topk_kernel<<<BATCH * NHEADS, 256, 0, stream>>>(M, Mtop, U);
  attn_flash<<<dim3(nsplit, BATCH * NHEADS), 256, 0, stream>>>(
      Qf, Kf, Vf, Mtop, part_ctx, part_m, part_l, U, nsplit, chunks_per_block);
  attn_combine<<<BATCH * NHEADS, 256, 0, stream>>>(
      part_ctx, part_m, part_l, ctxTop, U, nsplit);
  vmean_kernel<<<BATCH * NHEADS, 256, 0, stream>>>(Vf, Vm);
  base_out_kernel<<<BATCH, 256, 0, stream>>>(Vm, W_out, b_out, baseO);
  fill_out<<<(BATCH * LSEQ * (D_MODEL / 4)) / 256, 256, 0, stream>>>(baseO, out);
  delta_out_mfma<<<BATCH * NHEADS, 256, 0, stream>>>(
      ctxTop, Vm, Mtop, Wpl + (size_t)3 * 524288, out, U);
}